// Round 9
// baseline (691.581 us; speedup 1.0000x reference)
//
#include <hip/hip_runtime.h>

// Temporal GraphSAGE, P=4 periods, C=128, L=2 (reference constants).
// R14: 512-thread gemm blocks (256 rows) sharing ONE 64KB LDS weight panel.
// R13 PMC: gemm_fused latency-bound (MfmaUtil 4.5%, VALU 17.6%, HBM 16%,
// occupancy 16.9%) with LDS=64KB forcing 2 blocks/CU x 4 waves = 8 waves/CU.
// Same panel shared by 8 waves -> 16 waves/CU (2x latency hiding), halved
// per-row staging traffic. Math, gather order, and ordering mechanism are
// UNTOUCHED (bit-identical output to R13, absmax 0.13 regime).
// Carried: fused CSR gather into A2 fragments (f32 ascending order,
// start=row_ptr-dg; no aggk, no agg_bf round-trip); cursor-atomic fillk;
// permuted channel layout pi(c)=(c&15)*8+(c>>4); compact h rows; byte
// involvement flags; scan-based compaction; remapk via bucket ends.

#define CD 128

typedef __attribute__((ext_vector_type(8))) short s16x8;
typedef __attribute__((ext_vector_type(4))) float f32x4;

static __device__ __forceinline__ unsigned short f2bf(float f) {
  unsigned u = __float_as_uint(f);
  u += 0x7FFF + ((u >> 16) & 1);   // round-to-nearest-even
  return (unsigned short)(u >> 16);
}
static __device__ __forceinline__ float bf2f(unsigned us) {
  return __uint_as_float(us << 16);
}
static __device__ __forceinline__ void acc8(float* a, uint4 v) {
  a[0] += bf2f(v.x & 0xffffu); a[1] += bf2f(v.x >> 16);
  a[2] += bf2f(v.y & 0xffffu); a[3] += bf2f(v.y >> 16);
  a[4] += bf2f(v.z & 0xffffu); a[5] += bf2f(v.z >> 16);
  a[6] += bf2f(v.w & 0xffffu); a[7] += bf2f(v.w >> 16);
}
static __device__ __forceinline__ s16x8 pack8(const float* a, float sc) {
  s16x8 r;
#pragma unroll
  for (int j = 0; j < 8; ++j) r[j] = (short)f2bf(a[j] * sc);
  return r;
}

// ---- histogram: per-(period,dst) degree (atomic) + involvement bytes ----
__global__ __launch_bounds__(256) void histk(const int* __restrict__ ntime,
    const int* __restrict__ eidx, int* __restrict__ deg_pd,
    unsigned char* __restrict__ inv,
    const int* __restrict__ minp, const int* __restrict__ up, int N, int E) {
  int e = blockIdx.x * 256 + threadIdx.x;
  if (e >= E) return;
  int s = eidx[e], d = eidx[E + e];
  int ts = ntime[s], td = ntime[d];
  int m = ts > td ? ts : td;
  int p = (m - minp[0]) / up[0];
  atomicAdd(&deg_pd[p * N + d], 1);
  inv[(size_t)p * N + s] = 1;   // benign race: all writers store 1
  inv[(size_t)p * N + d] = 1;
}

// ---- compaction pass 1: per-block per-period involved counts ----
__global__ __launch_bounds__(256) void compcnt(const unsigned char* __restrict__ inv,
    int* __restrict__ bcnt, int NB2, int N) {
  int i = blockIdx.x * 256 + threadIdx.x;
  int bits = 0;
  if (i < N)
    bits = (int)inv[i] | ((int)inv[N + i] << 1)
         | ((int)inv[2 * (size_t)N + i] << 2) | ((int)inv[3 * (size_t)N + i] << 3);
  int wv = threadIdx.x >> 6;
  int lane = threadIdx.x & 63;
  __shared__ int wcnt[4][4];   // [period][wave]
#pragma unroll
  for (int p = 0; p < 4; ++p) {
    unsigned long long m = __ballot((bits >> p) & 1);
    if (lane == 0) wcnt[p][wv] = __popcll(m);
  }
  __syncthreads();
  if (threadIdx.x < 4) {
    int p = threadIdx.x;
    bcnt[p * NB2 + blockIdx.x] = wcnt[p][0] + wcnt[p][1] + wcnt[p][2] + wcnt[p][3];
  }
}

// ---- compaction pass 3: deterministic scatter + inverse map + ncnt totals ----
__global__ __launch_bounds__(256) void compscat(const unsigned char* __restrict__ inv,
    const int* __restrict__ bcnt, const int* __restrict__ bexc,
    int* __restrict__ nlist, int* __restrict__ cidx, int* __restrict__ ncnt,
    int NB2, int N) {
  int i = blockIdx.x * 256 + threadIdx.x;
  int bits = 0;
  if (i < N)
    bits = (int)inv[i] | ((int)inv[N + i] << 1)
         | ((int)inv[2 * (size_t)N + i] << 2) | ((int)inv[3 * (size_t)N + i] << 3);
  if (blockIdx.x == 0 && threadIdx.x < 4) {
    int p = threadIdx.x;
    ncnt[p] = bexc[p * NB2 + NB2 - 1] + bcnt[p * NB2 + NB2 - 1] - bexc[p * NB2];
  }
  int wv = threadIdx.x >> 6;
  int lane = threadIdx.x & 63;
  unsigned long long lanes_below = (lane == 0) ? 0ull : ((~0ull) >> (64 - lane));
  __shared__ int wcnt[4][4];
  unsigned long long mm[4];
#pragma unroll
  for (int p = 0; p < 4; ++p) {
    mm[p] = __ballot((bits >> p) & 1);
    if (lane == 0) wcnt[p][wv] = __popcll(mm[p]);
  }
  __syncthreads();
#pragma unroll
  for (int p = 0; p < 4; ++p) {
    if (!((bits >> p) & 1)) continue;
    int wpre = (wv > 0 ? wcnt[p][0] : 0) + (wv > 1 ? wcnt[p][1] : 0)
             + (wv > 2 ? wcnt[p][2] : 0);
    int base = bexc[p * NB2 + blockIdx.x] - bexc[p * NB2];
    int pos = base + wpre + __popcll(mm[p] & lanes_below);
    nlist[p * N + pos] = i;
    cidx[p * N + i] = pos;
  }
}

// ---- exclusive scan (3-phase) ----
__global__ __launch_bounds__(256) void scan1(const int* __restrict__ in,
    int* __restrict__ out, int* __restrict__ bsums, int M) {
  __shared__ int lds[256];
  int tid = threadIdx.x;
  int base = blockIdx.x * 1024 + tid * 4;
  int v0 = base + 0 < M ? in[base + 0] : 0;
  int v1 = base + 1 < M ? in[base + 1] : 0;
  int v2 = base + 2 < M ? in[base + 2] : 0;
  int v3 = base + 3 < M ? in[base + 3] : 0;
  int s = v0 + v1 + v2 + v3;
  lds[tid] = s;
  __syncthreads();
  for (int off = 1; off < 256; off <<= 1) {
    int t = tid >= off ? lds[tid - off] : 0;
    __syncthreads();
    lds[tid] += t;
    __syncthreads();
  }
  int run = lds[tid] - s;
  if (base + 0 < M) out[base + 0] = run; run += v0;
  if (base + 1 < M) out[base + 1] = run; run += v1;
  if (base + 2 < M) out[base + 2] = run; run += v2;
  if (base + 3 < M) out[base + 3] = run;
  if (tid == 255) bsums[blockIdx.x] = lds[255];
}

__global__ __launch_bounds__(256) void scan2(int* __restrict__ b, int M) {
  __shared__ int lds[256];
  int tid = threadIdx.x;
  int base = tid * 4;
  int v0 = base + 0 < M ? b[base + 0] : 0;
  int v1 = base + 1 < M ? b[base + 1] : 0;
  int v2 = base + 2 < M ? b[base + 2] : 0;
  int v3 = base + 3 < M ? b[base + 3] : 0;
  int s = v0 + v1 + v2 + v3;
  lds[tid] = s;
  __syncthreads();
  for (int off = 1; off < 256; off <<= 1) {
    int t = tid >= off ? lds[tid - off] : 0;
    __syncthreads();
    lds[tid] += t;
    __syncthreads();
  }
  int run = lds[tid] - s;
  if (base + 0 < M) b[base + 0] = run; run += v0;
  if (base + 1 < M) b[base + 1] = run; run += v1;
  if (base + 2 < M) b[base + 2] = run; run += v2;
  if (base + 3 < M) b[base + 3] = run;
}

__global__ __launch_bounds__(256) void scan3(int* __restrict__ out,
    const int* __restrict__ bsums, int M) {
  int add = bsums[blockIdx.x];
  int idx = blockIdx.x * 1024 + threadIdx.x;
#pragma unroll
  for (int k = 0; k < 4; ++k) {
    int i = idx + k * 256;
    if (i < M) out[i] += add;
  }
}

// ---- fill CSR col array; row_ptr doubles as cursor (R10 mechanism) ----
__global__ __launch_bounds__(256) void fillk(const int* __restrict__ ntime,
    const int* __restrict__ eidx, int* __restrict__ row_ptr, int* __restrict__ col,
    const int* __restrict__ minp, const int* __restrict__ up, int N, int E) {
  int e = blockIdx.x * 256 + threadIdx.x;
  if (e >= E) return;
  int s = eidx[e], d = eidx[E + e];
  int ts = ntime[s], td = ntime[d];
  int m = ts > td ? ts : td;
  int p = (m - minp[0]) / up[0];
  int pos = atomicAdd(&row_ptr[p * N + d], 1);
  col[pos] = s;
}

// ---- translate layer2 sources: col (node id) -> col2 (compact gi) ----
// row_ptr is post-cursor (bucket ENDS): period p ends at row_ptr[(p+1)*N-1].
__global__ __launch_bounds__(256) void remapk(const int* __restrict__ col,
    int* __restrict__ col2, const int* __restrict__ cidx,
    const int* __restrict__ row_ptr, int N, int E) {
  int i = blockIdx.x * 256 + threadIdx.x;
  if (i >= E) return;
  int p = (i >= row_ptr[N - 1]) + (i >= row_ptr[2 * N - 1]) + (i >= row_ptr[3 * N - 1]);
  col2[i] = cidx[(size_t)p * N + col[i]];
}

// ---- weights: bf16, fragment-linear, K-rows PERMUTED to match pi-layout ----
__global__ __launch_bounds__(256) void wprep(const float* __restrict__ wroot,
    const float* __restrict__ wnbr, unsigned short* __restrict__ wt, int total) {
  int t = blockIdx.x * 256 + threadIdx.x;
  if (t >= total) return;
  int l = t >> 12;
  int rem = t & 4095;
  int q = rem >> 7;
  int n = rem & 127;
  const float* src = (q < 16) ? (wroot + l * CD * CD) : (wnbr + l * CD * CD);
  int qh = q & 15;
  unsigned short o[8];
#pragma unroll
  for (int j = 0; j < 8; ++j) {
    int kp = qh * 8 + j;                 // permuted k within half
    int kt = (kp & 7) * 16 + (kp >> 3);  // true k
    o[j] = f2bf(src[kt * CD + n]);
  }
  uint4 pk;
  pk.x = (unsigned)o[0] | ((unsigned)o[1] << 16);
  pk.y = (unsigned)o[2] | ((unsigned)o[3] << 16);
  pk.z = (unsigned)o[4] | ((unsigned)o[5] << 16);
  pk.w = (unsigned)o[6] | ((unsigned)o[7] << 16);
  *(uint4*)(wt + (size_t)l * 32768 + ((size_t)q * CD + n) * 8) = pk;
}

// ---- x_bf init (permuted layout) + fp32 seed mirror ----
__global__ __launch_bounds__(256) void xprep(const float* __restrict__ x,
    unsigned short* __restrict__ xb, float* __restrict__ x32, int nseed, int total) {
  int t = blockIdx.x * 256 + threadIdx.x;
  if (t >= total) return;            // total = N*16
  int row = t >> 4, j = t & 15;
  const float* xp = x + (size_t)row * CD + j;
  bool seed = row < nseed;
  float* x3 = x32 + (size_t)row * CD + j;
  unsigned short o[8];
#pragma unroll
  for (int tt = 0; tt < 8; ++tt) {
    float v = xp[tt * 16];
    o[tt] = f2bf(v);
    if (seed) x3[tt * 16] = v;
  }
  uint4 pk;
  pk.x = (unsigned)o[0] | ((unsigned)o[1] << 16);
  pk.y = (unsigned)o[2] | ((unsigned)o[3] << 16);
  pk.z = (unsigned)o[4] | ((unsigned)o[5] << 16);
  pk.w = (unsigned)o[6] | ((unsigned)o[7] << 16);
  *(uint4*)(xb + (size_t)row * CD + j * 8) = pk;
}

// ---- FUSED gather-aggregate + MFMA GEMM + bias + LN ----
// 512 threads = 8 waves, 256 rows/block, ONE shared 64KB weight panel.
// A2 = mean over CSR neighbors, f32-accumulated in ascending CSR order with
// start = row_ptr[key]-dg  ==> bitwise-identical to R13/R10 output.
__global__ __launch_bounds__(512, 4) void gemm_fused(
    const unsigned short* __restrict__ feat,
    const unsigned short* __restrict__ wt,
    const float* __restrict__ bias, const float* __restrict__ lng,
    const float* __restrict__ lnb,
    unsigned short* __restrict__ hout,
    float* __restrict__ x32, unsigned short* __restrict__ xbf,
    const int* __restrict__ nlp, const int* __restrict__ pcnt,
    const int* __restrict__ deg_pd, const int* __restrict__ row_ptr,
    const int* __restrict__ cols,
    int p, int N, int mode, int nseed) {
  int cnt = pcnt[0];
  int rbase = blockIdx.x * 256;
  if (rbase >= cnt) return;

  __shared__ unsigned short Blds[32768];   // 64 KB: whole layer weight panel
  {
    const uint4* src = (const uint4*)wt;
    uint4* dst = (uint4*)Blds;
#pragma unroll
    for (int i = 0; i < 8; ++i) dst[threadIdx.x + i * 512] = src[threadIdx.x + i * 512];
  }
  // barrier deferred until after gather (gather doesn't touch LDS)

  int tid = threadIdx.x;
  int w = tid >> 6;
  int lane = tid & 63;
  int l15 = lane & 15;
  int quad = lane >> 4;

  // per-lane A rows + CSR metadata (clamped; dup work discarded in epilogue)
  int dg_[2], st_[2];
  const unsigned short* b1[2];
#pragma unroll
  for (int rt = 0; rt < 2; ++rt) {
    int ii = rbase + w * 32 + rt * 16 + l15;
    ii = ii < cnt ? ii : cnt - 1;
    int node = nlp[ii];
    int key = p * N + node;
    int dg = deg_pd[key];
    dg_[rt] = dg;
    st_[rt] = row_ptr[key] - dg;          // cursor end - deg = bucket start
    b1[rt] = feat + (size_t)(mode == 0 ? node : ii) * CD;
  }

  s16x8 af[4][2][2];
  // A1 fragments (kc 0..1)
#pragma unroll
  for (int kc = 0; kc < 2; ++kc)
#pragma unroll
    for (int ks = 0; ks < 2; ++ks) {
      int off = kc * 64 + (ks * 4 + quad) * 8;
#pragma unroll
      for (int rt = 0; rt < 2; ++rt)
        af[kc][ks][rt] = *(const s16x8*)(b1[rt] + off);
    }

  // A2 fragments (kc 2..3): fused CSR gather + mean (f32, ascending order)
  int cb = quad * 8;
#pragma unroll
  for (int rt = 0; rt < 2; ++rt) {
    float a0[8], a1[8], a2[8], a3[8];
#pragma unroll
    for (int j = 0; j < 8; ++j) { a0[j] = 0.f; a1[j] = 0.f; a2[j] = 0.f; a3[j] = 0.f; }
    int dg = dg_[rt], st = st_[rt];
    for (int j = 0; j < dg; ++j) {
      int r = cols[st + j];
      const unsigned short* rp = feat + (size_t)r * CD;
      uint4 v0 = *(const uint4*)(rp + cb);
      uint4 v1 = *(const uint4*)(rp + cb + 32);
      uint4 v2 = *(const uint4*)(rp + cb + 64);
      uint4 v3 = *(const uint4*)(rp + cb + 96);
      acc8(a0, v0); acc8(a1, v1); acc8(a2, v2); acc8(a3, v3);
    }
    float sc = dg > 0 ? 1.0f / (float)dg : 0.f;
    af[2][0][rt] = pack8(a0, sc);
    af[2][1][rt] = pack8(a1, sc);
    af[3][0][rt] = pack8(a2, sc);
    af[3][1][rt] = pack8(a3, sc);
  }

  __syncthreads();   // B panel ready (staged during gather)

  f32x4 acc[2][8];
#pragma unroll
  for (int rt = 0; rt < 2; ++rt)
#pragma unroll
    for (int ct = 0; ct < 8; ++ct) acc[rt][ct] = (f32x4)(0.f);

#pragma unroll
  for (int kc = 0; kc < 4; ++kc) {
#pragma unroll
    for (int ks = 0; ks < 2; ++ks) {
      int q = kc * 8 + ks * 4 + quad;        // global 16B k-block in [0,32)
      s16x8 bfr[8];
#pragma unroll
      for (int ct = 0; ct < 8; ++ct)
        bfr[ct] = *(const s16x8*)&Blds[((size_t)q * CD + l15) * 8 + (size_t)ct * 128];
#pragma unroll
      for (int rt = 0; rt < 2; ++rt)
#pragma unroll
        for (int ct = 0; ct < 8; ++ct)
          acc[rt][ct] = __builtin_amdgcn_mfma_f32_16x16x32_bf16(
              af[kc][ks][rt], bfr[ct], acc[rt][ct], 0, 0, 0);
    }
  }

  // epilogue: bias + LayerNorm across the 16-lane row group (true col = ct*16+l15)
  float bb[8], gg[8], eb[8];
#pragma unroll
  for (int ct = 0; ct < 8; ++ct) {
    int c = ct * 16 + l15;
    bb[ct] = bias[c]; gg[ct] = lng[c]; eb[ct] = lnb[c];
  }
#pragma unroll
  for (int rt = 0; rt < 2; ++rt) {
#pragma unroll
    for (int reg = 0; reg < 4; ++reg) {
      int ridx = rbase + w * 32 + rt * 16 + quad * 4 + reg;
      float vals[8];
      float s = 0.f, ss = 0.f;
#pragma unroll
      for (int ct = 0; ct < 8; ++ct) {
        float v = acc[rt][ct][reg] + bb[ct];
        vals[ct] = v;
        s += v; ss += v * v;
      }
#pragma unroll
      for (int m = 1; m <= 8; m <<= 1) {
        s  += __shfl_xor(s, m, 64);
        ss += __shfl_xor(ss, m, 64);
      }
      float mu  = s * (1.0f / CD);
      float var = ss * (1.0f / CD) - mu * mu;
      float rs  = rsqrtf(var + 1e-5f);
      if (ridx < cnt) {
        float o[8];
#pragma unroll
        for (int ct = 0; ct < 8; ++ct) o[ct] = (vals[ct] - mu) * rs * gg[ct] + eb[ct];
        if (mode == 0) {
          uint4 pk;
          pk.x = (unsigned)f2bf(fmaxf(o[0], 0.f)) | ((unsigned)f2bf(fmaxf(o[1], 0.f)) << 16);
          pk.y = (unsigned)f2bf(fmaxf(o[2], 0.f)) | ((unsigned)f2bf(fmaxf(o[3], 0.f)) << 16);
          pk.z = (unsigned)f2bf(fmaxf(o[4], 0.f)) | ((unsigned)f2bf(fmaxf(o[5], 0.f)) << 16);
          pk.w = (unsigned)f2bf(fmaxf(o[6], 0.f)) | ((unsigned)f2bf(fmaxf(o[7], 0.f)) << 16);
          *(uint4*)(hout + (size_t)ridx * CD + l15 * 8) = pk;   // compact, sequential
        } else {
          int node = nlp[ridx];
          unsigned short* xp = xbf + (size_t)node * CD + l15 * 8;
          uint4 old = *(const uint4*)xp;
          float xn0 = bf2f(old.x & 0xffffu) + o[0], xn1 = bf2f(old.x >> 16) + o[1];
          float xn2 = bf2f(old.y & 0xffffu) + o[2], xn3 = bf2f(old.y >> 16) + o[3];
          float xn4 = bf2f(old.z & 0xffffu) + o[4], xn5 = bf2f(old.z >> 16) + o[5];
          float xn6 = bf2f(old.w & 0xffffu) + o[6], xn7 = bf2f(old.w >> 16) + o[7];
          uint4 pk;
          pk.x = (unsigned)f2bf(xn0) | ((unsigned)f2bf(xn1) << 16);
          pk.y = (unsigned)f2bf(xn2) | ((unsigned)f2bf(xn3) << 16);
          pk.z = (unsigned)f2bf(xn4) | ((unsigned)f2bf(xn5) << 16);
          pk.w = (unsigned)f2bf(xn6) | ((unsigned)f2bf(xn7) << 16);
          *(uint4*)xp = pk;
          if (node < nseed) {
            float* x3 = x32 + (size_t)node * CD + l15;
#pragma unroll
            for (int ct = 0; ct < 8; ++ct) x3[ct * 16] += o[ct];
          }
        }
      }
    }
  }
}

// ---- head (reads fp32 seed mirror, original layout) ----
__global__ __launch_bounds__(256) void headk(const float* __restrict__ x,
    const float* __restrict__ hw, const float* __restrict__ hb,
    float* __restrict__ out, int seeds) {
  int wave = threadIdx.x >> 6;
  int lane = threadIdx.x & 63;
  int row = blockIdx.x * 4 + wave;
  if (row >= seeds) return;
  const float* xp = x + (size_t)row * CD;
  float v = xp[lane] * hw[lane] + xp[64 + lane] * hw[64 + lane];
#pragma unroll
  for (int m = 1; m < 64; m <<= 1) v += __shfl_xor(v, m, 64);
  if (lane == 0) out[row] = v + hb[0];
}

extern "C" void kernel_launch(void* const* d_in, const int* in_sizes, int n_in,
                              void* d_out, int out_size, void* d_ws, size_t ws_size,
                              hipStream_t stream) {
  const float* x     = (const float*)d_in[0];
  const int*   ntime = (const int*)d_in[1];
  const int*   eidx  = (const int*)d_in[2];
  const float* wroot = (const float*)d_in[3];
  const float* wnbr  = (const float*)d_in[4];
  const float* bias  = (const float*)d_in[5];
  const float* lng   = (const float*)d_in[6];
  const float* lnb   = (const float*)d_in[7];
  const float* headw = (const float*)d_in[8];
  const float* headb = (const float*)d_in[9];
  const int*   minp  = (const int*)d_in[10];
  const int*   up    = (const int*)d_in[12];

  int N = in_sizes[0] / CD;
  int E = in_sizes[2] / 2;
  const int P = 4;
  int M = P * N;
  int nseed = out_size;   // OUT=1 per reference

  size_t off = 0;
  auto alloc = [&](size_t bytes) {
    void* p = (char*)d_ws + off;
    off += (bytes + 255) & ~(size_t)255;
    return p;
  };
  unsigned short* x_bf = (unsigned short*)alloc((size_t)N * CD * 2);
  unsigned short* h_bf = (unsigned short*)alloc((size_t)N * CD * 2);   // compact rows
  float*          x32  = (float*)alloc((size_t)nseed * CD * 4);
  unsigned short* wt   = (unsigned short*)alloc(2 * 32768 * 2);
  int* deg_pd   = (int*)alloc((size_t)M * 4);
  int* row_ptr  = (int*)alloc((size_t)M * 4);
  int* col      = (int*)alloc((size_t)E * 4);
  int* col2     = (int*)alloc((size_t)E * 4);
  unsigned char* inv = (unsigned char*)alloc((size_t)M);   // [p][node] flags
  int* nlist    = (int*)alloc((size_t)M * 4);
  int* cidx     = (int*)alloc((size_t)M * 4);
  int* ncnt     = (int*)alloc(256);
  int* bsums    = (int*)alloc(4096);

  int NB2 = (N + 255) / 256;               // compaction blocks
  int M2 = 4 * NB2;                        // bcnt/bexc length
  int* bcnt = (int*)alloc((size_t)M2 * 4);
  int* bexc = (int*)alloc((size_t)M2 * 4);
  (void)ws_size;

  hipMemsetAsync(deg_pd, 0, (size_t)M * 4, stream);
  hipMemsetAsync(inv, 0, (size_t)M, stream);

  int egrid = (E + 255) / 256;
  int NB = (M + 1023) / 1024;
  int NBc = (M2 + 1023) / 1024;
  int ggrid = (N + 255) / 256;             // 256 rows per gemm block

  xprep<<<(N * 16 + 255) / 256, 256, 0, stream>>>(x, x_bf, x32, nseed, N * 16);
  wprep<<<(8192 + 255) / 256, 256, 0, stream>>>(wroot, wnbr, wt, 8192);
  histk<<<egrid, 256, 0, stream>>>(ntime, eidx, deg_pd, inv, minp, up, N, E);

  // compaction: count -> scan -> scatter (+ node->gi map, + ncnt totals)
  compcnt<<<NB2, 256, 0, stream>>>(inv, bcnt, NB2, N);
  scan1<<<NBc, 256, 0, stream>>>(bcnt, bexc, bsums, M2);
  scan2<<<1, 256, 0, stream>>>(bsums, NBc);
  scan3<<<NBc, 256, 0, stream>>>(bexc, bsums, M2);
  compscat<<<NB2, 256, 0, stream>>>(inv, bcnt, bexc, nlist, cidx, ncnt, NB2, N);

  // CSR build (cursor mechanism: row_ptr advances to bucket ends)
  scan1<<<NB, 256, 0, stream>>>(deg_pd, row_ptr, bsums, M);
  scan2<<<1, 256, 0, stream>>>(bsums, NB);
  scan3<<<NB, 256, 0, stream>>>(row_ptr, bsums, M);
  fillk<<<egrid, 256, 0, stream>>>(ntime, eidx, row_ptr, col, minp, up, N, E);
  remapk<<<egrid, 256, 0, stream>>>(col, col2, cidx, row_ptr, N, E);

  for (int p = 0; p < P; ++p) {
    const int* nlp = nlist + (size_t)p * N;
    const int* pc  = ncnt + p;
    gemm_fused<<<ggrid, 512, 0, stream>>>(x_bf, wt,
        bias, lng, lnb, h_bf, nullptr, nullptr, nlp, pc,
        deg_pd, row_ptr, col, p, N, 0, nseed);
    gemm_fused<<<ggrid, 512, 0, stream>>>(h_bf, wt + 32768,
        bias + CD, lng + CD, lnb + CD, nullptr, x32, x_bf, nlp, pc,
        deg_pd, row_ptr, col2, p, N, 1, nseed);
  }
  headk<<<(nseed + 3) / 4, 256, 0, stream>>>(x32, headw, headb, (float*)d_out, nseed);
}

// Round 10
// 646.219 us; speedup vs baseline: 1.0702x; 1.0702x over previous
//
#include <hip/hip_runtime.h>

// Temporal GraphSAGE, P=4 periods, C=128, L=2 (reference constants).
// R15: R14's 512-thread/256-row retile with the spill fixed. R14 PMC:
// __launch_bounds__(512,4) capped VGPR at 64 -> accumulator spill to
// scratch (WRITE_SIZE 42->143MB, FETCH 74->123MB, gemm 90->100us despite
// occupancy 17->28%). Now __launch_bounds__(512,2) (VGPR cap 256, compiler
// needs ~104) -> no spill; HW still fits 4 waves/SIMD at 104 VGPR and LDS
// fits 2 blocks/CU -> 16 waves/CU with R13's clean memory profile.
// Math, gather order, ordering mechanism UNTOUCHED.
// Carried: fused CSR gather into A2 fragments (f32 ascending order,
// start=row_ptr-dg; no aggk/agg_bf); cursor-atomic fillk; permuted channel
// layout pi(c)=(c&15)*8+(c>>4); compact h rows; one shared 64KB LDS weight
// panel per block; byte involvement flags; scan-based compaction; remapk.

#define CD 128

typedef __attribute__((ext_vector_type(8))) short s16x8;
typedef __attribute__((ext_vector_type(4))) float f32x4;

static __device__ __forceinline__ unsigned short f2bf(float f) {
  unsigned u = __float_as_uint(f);
  u += 0x7FFF + ((u >> 16) & 1);   // round-to-nearest-even
  return (unsigned short)(u >> 16);
}
static __device__ __forceinline__ float bf2f(unsigned us) {
  return __uint_as_float(us << 16);
}
static __device__ __forceinline__ void acc8(float* a, uint4 v) {
  a[0] += bf2f(v.x & 0xffffu); a[1] += bf2f(v.x >> 16);
  a[2] += bf2f(v.y & 0xffffu); a[3] += bf2f(v.y >> 16);
  a[4] += bf2f(v.z & 0xffffu); a[5] += bf2f(v.z >> 16);
  a[6] += bf2f(v.w & 0xffffu); a[7] += bf2f(v.w >> 16);
}
static __device__ __forceinline__ s16x8 pack8(const float* a, float sc) {
  s16x8 r;
#pragma unroll
  for (int j = 0; j < 8; ++j) r[j] = (short)f2bf(a[j] * sc);
  return r;
}

// ---- histogram: per-(period,dst) degree (atomic) + involvement bytes ----
__global__ __launch_bounds__(256) void histk(const int* __restrict__ ntime,
    const int* __restrict__ eidx, int* __restrict__ deg_pd,
    unsigned char* __restrict__ inv,
    const int* __restrict__ minp, const int* __restrict__ up, int N, int E) {
  int e = blockIdx.x * 256 + threadIdx.x;
  if (e >= E) return;
  int s = eidx[e], d = eidx[E + e];
  int ts = ntime[s], td = ntime[d];
  int m = ts > td ? ts : td;
  int p = (m - minp[0]) / up[0];
  atomicAdd(&deg_pd[p * N + d], 1);
  inv[(size_t)p * N + s] = 1;   // benign race: all writers store 1
  inv[(size_t)p * N + d] = 1;
}

// ---- compaction pass 1: per-block per-period involved counts ----
__global__ __launch_bounds__(256) void compcnt(const unsigned char* __restrict__ inv,
    int* __restrict__ bcnt, int NB2, int N) {
  int i = blockIdx.x * 256 + threadIdx.x;
  int bits = 0;
  if (i < N)
    bits = (int)inv[i] | ((int)inv[N + i] << 1)
         | ((int)inv[2 * (size_t)N + i] << 2) | ((int)inv[3 * (size_t)N + i] << 3);
  int wv = threadIdx.x >> 6;
  int lane = threadIdx.x & 63;
  __shared__ int wcnt[4][4];   // [period][wave]
#pragma unroll
  for (int p = 0; p < 4; ++p) {
    unsigned long long m = __ballot((bits >> p) & 1);
    if (lane == 0) wcnt[p][wv] = __popcll(m);
  }
  __syncthreads();
  if (threadIdx.x < 4) {
    int p = threadIdx.x;
    bcnt[p * NB2 + blockIdx.x] = wcnt[p][0] + wcnt[p][1] + wcnt[p][2] + wcnt[p][3];
  }
}

// ---- compaction pass 3: deterministic scatter + inverse map + ncnt totals ----
__global__ __launch_bounds__(256) void compscat(const unsigned char* __restrict__ inv,
    const int* __restrict__ bcnt, const int* __restrict__ bexc,
    int* __restrict__ nlist, int* __restrict__ cidx, int* __restrict__ ncnt,
    int NB2, int N) {
  int i = blockIdx.x * 256 + threadIdx.x;
  int bits = 0;
  if (i < N)
    bits = (int)inv[i] | ((int)inv[N + i] << 1)
         | ((int)inv[2 * (size_t)N + i] << 2) | ((int)inv[3 * (size_t)N + i] << 3);
  if (blockIdx.x == 0 && threadIdx.x < 4) {
    int p = threadIdx.x;
    ncnt[p] = bexc[p * NB2 + NB2 - 1] + bcnt[p * NB2 + NB2 - 1] - bexc[p * NB2];
  }
  int wv = threadIdx.x >> 6;
  int lane = threadIdx.x & 63;
  unsigned long long lanes_below = (lane == 0) ? 0ull : ((~0ull) >> (64 - lane));
  __shared__ int wcnt[4][4];
  unsigned long long mm[4];
#pragma unroll
  for (int p = 0; p < 4; ++p) {
    mm[p] = __ballot((bits >> p) & 1);
    if (lane == 0) wcnt[p][wv] = __popcll(mm[p]);
  }
  __syncthreads();
#pragma unroll
  for (int p = 0; p < 4; ++p) {
    if (!((bits >> p) & 1)) continue;
    int wpre = (wv > 0 ? wcnt[p][0] : 0) + (wv > 1 ? wcnt[p][1] : 0)
             + (wv > 2 ? wcnt[p][2] : 0);
    int base = bexc[p * NB2 + blockIdx.x] - bexc[p * NB2];
    int pos = base + wpre + __popcll(mm[p] & lanes_below);
    nlist[p * N + pos] = i;
    cidx[p * N + i] = pos;
  }
}

// ---- exclusive scan (3-phase) ----
__global__ __launch_bounds__(256) void scan1(const int* __restrict__ in,
    int* __restrict__ out, int* __restrict__ bsums, int M) {
  __shared__ int lds[256];
  int tid = threadIdx.x;
  int base = blockIdx.x * 1024 + tid * 4;
  int v0 = base + 0 < M ? in[base + 0] : 0;
  int v1 = base + 1 < M ? in[base + 1] : 0;
  int v2 = base + 2 < M ? in[base + 2] : 0;
  int v3 = base + 3 < M ? in[base + 3] : 0;
  int s = v0 + v1 + v2 + v3;
  lds[tid] = s;
  __syncthreads();
  for (int off = 1; off < 256; off <<= 1) {
    int t = tid >= off ? lds[tid - off] : 0;
    __syncthreads();
    lds[tid] += t;
    __syncthreads();
  }
  int run = lds[tid] - s;
  if (base + 0 < M) out[base + 0] = run; run += v0;
  if (base + 1 < M) out[base + 1] = run; run += v1;
  if (base + 2 < M) out[base + 2] = run; run += v2;
  if (base + 3 < M) out[base + 3] = run;
  if (tid == 255) bsums[blockIdx.x] = lds[255];
}

__global__ __launch_bounds__(256) void scan2(int* __restrict__ b, int M) {
  __shared__ int lds[256];
  int tid = threadIdx.x;
  int base = tid * 4;
  int v0 = base + 0 < M ? b[base + 0] : 0;
  int v1 = base + 1 < M ? b[base + 1] : 0;
  int v2 = base + 2 < M ? b[base + 2] : 0;
  int v3 = base + 3 < M ? b[base + 3] : 0;
  int s = v0 + v1 + v2 + v3;
  lds[tid] = s;
  __syncthreads();
  for (int off = 1; off < 256; off <<= 1) {
    int t = tid >= off ? lds[tid - off] : 0;
    __syncthreads();
    lds[tid] += t;
    __syncthreads();
  }
  int run = lds[tid] - s;
  if (base + 0 < M) b[base + 0] = run; run += v0;
  if (base + 1 < M) b[base + 1] = run; run += v1;
  if (base + 2 < M) b[base + 2] = run; run += v2;
  if (base + 3 < M) b[base + 3] = run;
}

__global__ __launch_bounds__(256) void scan3(int* __restrict__ out,
    const int* __restrict__ bsums, int M) {
  int add = bsums[blockIdx.x];
  int idx = blockIdx.x * 1024 + threadIdx.x;
#pragma unroll
  for (int k = 0; k < 4; ++k) {
    int i = idx + k * 256;
    if (i < M) out[i] += add;
  }
}

// ---- fill CSR col array; row_ptr doubles as cursor (R10 mechanism) ----
__global__ __launch_bounds__(256) void fillk(const int* __restrict__ ntime,
    const int* __restrict__ eidx, int* __restrict__ row_ptr, int* __restrict__ col,
    const int* __restrict__ minp, const int* __restrict__ up, int N, int E) {
  int e = blockIdx.x * 256 + threadIdx.x;
  if (e >= E) return;
  int s = eidx[e], d = eidx[E + e];
  int ts = ntime[s], td = ntime[d];
  int m = ts > td ? ts : td;
  int p = (m - minp[0]) / up[0];
  int pos = atomicAdd(&row_ptr[p * N + d], 1);
  col[pos] = s;
}

// ---- translate layer2 sources: col (node id) -> col2 (compact gi) ----
// row_ptr is post-cursor (bucket ENDS): period p ends at row_ptr[(p+1)*N-1].
__global__ __launch_bounds__(256) void remapk(const int* __restrict__ col,
    int* __restrict__ col2, const int* __restrict__ cidx,
    const int* __restrict__ row_ptr, int N, int E) {
  int i = blockIdx.x * 256 + threadIdx.x;
  if (i >= E) return;
  int p = (i >= row_ptr[N - 1]) + (i >= row_ptr[2 * N - 1]) + (i >= row_ptr[3 * N - 1]);
  col2[i] = cidx[(size_t)p * N + col[i]];
}

// ---- weights: bf16, fragment-linear, K-rows PERMUTED to match pi-layout ----
__global__ __launch_bounds__(256) void wprep(const float* __restrict__ wroot,
    const float* __restrict__ wnbr, unsigned short* __restrict__ wt, int total) {
  int t = blockIdx.x * 256 + threadIdx.x;
  if (t >= total) return;
  int l = t >> 12;
  int rem = t & 4095;
  int q = rem >> 7;
  int n = rem & 127;
  const float* src = (q < 16) ? (wroot + l * CD * CD) : (wnbr + l * CD * CD);
  int qh = q & 15;
  unsigned short o[8];
#pragma unroll
  for (int j = 0; j < 8; ++j) {
    int kp = qh * 8 + j;                 // permuted k within half
    int kt = (kp & 7) * 16 + (kp >> 3);  // true k
    o[j] = f2bf(src[kt * CD + n]);
  }
  uint4 pk;
  pk.x = (unsigned)o[0] | ((unsigned)o[1] << 16);
  pk.y = (unsigned)o[2] | ((unsigned)o[3] << 16);
  pk.z = (unsigned)o[4] | ((unsigned)o[5] << 16);
  pk.w = (unsigned)o[6] | ((unsigned)o[7] << 16);
  *(uint4*)(wt + (size_t)l * 32768 + ((size_t)q * CD + n) * 8) = pk;
}

// ---- x_bf init (permuted layout) + fp32 seed mirror ----
__global__ __launch_bounds__(256) void xprep(const float* __restrict__ x,
    unsigned short* __restrict__ xb, float* __restrict__ x32, int nseed, int total) {
  int t = blockIdx.x * 256 + threadIdx.x;
  if (t >= total) return;            // total = N*16
  int row = t >> 4, j = t & 15;
  const float* xp = x + (size_t)row * CD + j;
  bool seed = row < nseed;
  float* x3 = x32 + (size_t)row * CD + j;
  unsigned short o[8];
#pragma unroll
  for (int tt = 0; tt < 8; ++tt) {
    float v = xp[tt * 16];
    o[tt] = f2bf(v);
    if (seed) x3[tt * 16] = v;
  }
  uint4 pk;
  pk.x = (unsigned)o[0] | ((unsigned)o[1] << 16);
  pk.y = (unsigned)o[2] | ((unsigned)o[3] << 16);
  pk.z = (unsigned)o[4] | ((unsigned)o[5] << 16);
  pk.w = (unsigned)o[6] | ((unsigned)o[7] << 16);
  *(uint4*)(xb + (size_t)row * CD + j * 8) = pk;
}

// ---- FUSED gather-aggregate + MFMA GEMM + bias + LN ----
// 512 threads = 8 waves, 256 rows/block, ONE shared 64KB weight panel.
// A2 = mean over CSR neighbors, f32-accumulated in ascending CSR order with
// start = row_ptr[key]-dg  ==> bitwise-identical to R13/R10 output.
__global__ __launch_bounds__(512, 2) void gemm_fused(
    const unsigned short* __restrict__ feat,
    const unsigned short* __restrict__ wt,
    const float* __restrict__ bias, const float* __restrict__ lng,
    const float* __restrict__ lnb,
    unsigned short* __restrict__ hout,
    float* __restrict__ x32, unsigned short* __restrict__ xbf,
    const int* __restrict__ nlp, const int* __restrict__ pcnt,
    const int* __restrict__ deg_pd, const int* __restrict__ row_ptr,
    const int* __restrict__ cols,
    int p, int N, int mode, int nseed) {
  int cnt = pcnt[0];
  int rbase = blockIdx.x * 256;
  if (rbase >= cnt) return;

  __shared__ unsigned short Blds[32768];   // 64 KB: whole layer weight panel
  {
    const uint4* src = (const uint4*)wt;
    uint4* dst = (uint4*)Blds;
#pragma unroll
    for (int i = 0; i < 8; ++i) dst[threadIdx.x + i * 512] = src[threadIdx.x + i * 512];
  }
  // barrier deferred until after gather (gather doesn't touch LDS)

  int tid = threadIdx.x;
  int w = tid >> 6;
  int lane = tid & 63;
  int l15 = lane & 15;
  int quad = lane >> 4;

  // per-lane A rows + CSR metadata (clamped; dup work discarded in epilogue)
  int dg_[2], st_[2];
  const unsigned short* b1[2];
#pragma unroll
  for (int rt = 0; rt < 2; ++rt) {
    int ii = rbase + w * 32 + rt * 16 + l15;
    ii = ii < cnt ? ii : cnt - 1;
    int node = nlp[ii];
    int key = p * N + node;
    int dg = deg_pd[key];
    dg_[rt] = dg;
    st_[rt] = row_ptr[key] - dg;          // cursor end - deg = bucket start
    b1[rt] = feat + (size_t)(mode == 0 ? node : ii) * CD;
  }

  s16x8 af[4][2][2];
  // A1 fragments (kc 0..1)
#pragma unroll
  for (int kc = 0; kc < 2; ++kc)
#pragma unroll
    for (int ks = 0; ks < 2; ++ks) {
      int off = kc * 64 + (ks * 4 + quad) * 8;
#pragma unroll
      for (int rt = 0; rt < 2; ++rt)
        af[kc][ks][rt] = *(const s16x8*)(b1[rt] + off);
    }

  // A2 fragments (kc 2..3): fused CSR gather + mean (f32, ascending order)
  int cb = quad * 8;
#pragma unroll
  for (int rt = 0; rt < 2; ++rt) {
    float a0[8], a1[8], a2[8], a3[8];
#pragma unroll
    for (int j = 0; j < 8; ++j) { a0[j] = 0.f; a1[j] = 0.f; a2[j] = 0.f; a3[j] = 0.f; }
    int dg = dg_[rt], st = st_[rt];
    for (int j = 0; j < dg; ++j) {
      int r = cols[st + j];
      const unsigned short* rp = feat + (size_t)r * CD;
      uint4 v0 = *(const uint4*)(rp + cb);
      uint4 v1 = *(const uint4*)(rp + cb + 32);
      uint4 v2 = *(const uint4*)(rp + cb + 64);
      uint4 v3 = *(const uint4*)(rp + cb + 96);
      acc8(a0, v0); acc8(a1, v1); acc8(a2, v2); acc8(a3, v3);
    }
    float sc = dg > 0 ? 1.0f / (float)dg : 0.f;
    af[2][0][rt] = pack8(a0, sc);
    af[2][1][rt] = pack8(a1, sc);
    af[3][0][rt] = pack8(a2, sc);
    af[3][1][rt] = pack8(a3, sc);
  }

  __syncthreads();   // B panel ready (staged during gather)

  f32x4 acc[2][8];
#pragma unroll
  for (int rt = 0; rt < 2; ++rt)
#pragma unroll
    for (int ct = 0; ct < 8; ++ct) acc[rt][ct] = (f32x4)(0.f);

#pragma unroll
  for (int kc = 0; kc < 4; ++kc) {
#pragma unroll
    for (int ks = 0; ks < 2; ++ks) {
      int q = kc * 8 + ks * 4 + quad;        // global 16B k-block in [0,32)
      s16x8 bfr[8];
#pragma unroll
      for (int ct = 0; ct < 8; ++ct)
        bfr[ct] = *(const s16x8*)&Blds[((size_t)q * CD + l15) * 8 + (size_t)ct * 128];
#pragma unroll
      for (int rt = 0; rt < 2; ++rt)
#pragma unroll
        for (int ct = 0; ct < 8; ++ct)
          acc[rt][ct] = __builtin_amdgcn_mfma_f32_16x16x32_bf16(
              af[kc][ks][rt], bfr[ct], acc[rt][ct], 0, 0, 0);
    }
  }

  // epilogue: bias + LayerNorm across the 16-lane row group (true col = ct*16+l15)
  float bb[8], gg[8], eb[8];
#pragma unroll
  for (int ct = 0; ct < 8; ++ct) {
    int c = ct * 16 + l15;
    bb[ct] = bias[c]; gg[ct] = lng[c]; eb[ct] = lnb[c];
  }
#pragma unroll
  for (int rt = 0; rt < 2; ++rt) {
#pragma unroll
    for (int reg = 0; reg < 4; ++reg) {
      int ridx = rbase + w * 32 + rt * 16 + quad * 4 + reg;
      float vals[8];
      float s = 0.f, ss = 0.f;
#pragma unroll
      for (int ct = 0; ct < 8; ++ct) {
        float v = acc[rt][ct][reg] + bb[ct];
        vals[ct] = v;
        s += v; ss += v * v;
      }
#pragma unroll
      for (int m = 1; m <= 8; m <<= 1) {
        s  += __shfl_xor(s, m, 64);
        ss += __shfl_xor(ss, m, 64);
      }
      float mu  = s * (1.0f / CD);
      float var = ss * (1.0f / CD) - mu * mu;
      float rs  = rsqrtf(var + 1e-5f);
      if (ridx < cnt) {
        float o[8];
#pragma unroll
        for (int ct = 0; ct < 8; ++ct) o[ct] = (vals[ct] - mu) * rs * gg[ct] + eb[ct];
        if (mode == 0) {
          uint4 pk;
          pk.x = (unsigned)f2bf(fmaxf(o[0], 0.f)) | ((unsigned)f2bf(fmaxf(o[1], 0.f)) << 16);
          pk.y = (unsigned)f2bf(fmaxf(o[2], 0.f)) | ((unsigned)f2bf(fmaxf(o[3], 0.f)) << 16);
          pk.z = (unsigned)f2bf(fmaxf(o[4], 0.f)) | ((unsigned)f2bf(fmaxf(o[5], 0.f)) << 16);
          pk.w = (unsigned)f2bf(fmaxf(o[6], 0.f)) | ((unsigned)f2bf(fmaxf(o[7], 0.f)) << 16);
          *(uint4*)(hout + (size_t)ridx * CD + l15 * 8) = pk;   // compact, sequential
        } else {
          int node = nlp[ridx];
          unsigned short* xp = xbf + (size_t)node * CD + l15 * 8;
          uint4 old = *(const uint4*)xp;
          float xn0 = bf2f(old.x & 0xffffu) + o[0], xn1 = bf2f(old.x >> 16) + o[1];
          float xn2 = bf2f(old.y & 0xffffu) + o[2], xn3 = bf2f(old.y >> 16) + o[3];
          float xn4 = bf2f(old.z & 0xffffu) + o[4], xn5 = bf2f(old.z >> 16) + o[5];
          float xn6 = bf2f(old.w & 0xffffu) + o[6], xn7 = bf2f(old.w >> 16) + o[7];
          uint4 pk;
          pk.x = (unsigned)f2bf(xn0) | ((unsigned)f2bf(xn1) << 16);
          pk.y = (unsigned)f2bf(xn2) | ((unsigned)f2bf(xn3) << 16);
          pk.z = (unsigned)f2bf(xn4) | ((unsigned)f2bf(xn5) << 16);
          pk.w = (unsigned)f2bf(xn6) | ((unsigned)f2bf(xn7) << 16);
          *(uint4*)xp = pk;
          if (node < nseed) {
            float* x3 = x32 + (size_t)node * CD + l15;
#pragma unroll
            for (int ct = 0; ct < 8; ++ct) x3[ct * 16] += o[ct];
          }
        }
      }
    }
  }
}

// ---- head (reads fp32 seed mirror, original layout) ----
__global__ __launch_bounds__(256) void headk(const float* __restrict__ x,
    const float* __restrict__ hw, const float* __restrict__ hb,
    float* __restrict__ out, int seeds) {
  int wave = threadIdx.x >> 6;
  int lane = threadIdx.x & 63;
  int row = blockIdx.x * 4 + wave;
  if (row >= seeds) return;
  const float* xp = x + (size_t)row * CD;
  float v = xp[lane] * hw[lane] + xp[64 + lane] * hw[64 + lane];
#pragma unroll
  for (int m = 1; m < 64; m <<= 1) v += __shfl_xor(v, m, 64);
  if (lane == 0) out[row] = v + hb[0];
}

extern "C" void kernel_launch(void* const* d_in, const int* in_sizes, int n_in,
                              void* d_out, int out_size, void* d_ws, size_t ws_size,
                              hipStream_t stream) {
  const float* x     = (const float*)d_in[0];
  const int*   ntime = (const int*)d_in[1];
  const int*   eidx  = (const int*)d_in[2];
  const float* wroot = (const float*)d_in[3];
  const float* wnbr  = (const float*)d_in[4];
  const float* bias  = (const float*)d_in[5];
  const float* lng   = (const float*)d_in[6];
  const float* lnb   = (const float*)d_in[7];
  const float* headw = (const float*)d_in[8];
  const float* headb = (const float*)d_in[9];
  const int*   minp  = (const int*)d_in[10];
  const int*   up    = (const int*)d_in[12];

  int N = in_sizes[0] / CD;
  int E = in_sizes[2] / 2;
  const int P = 4;
  int M = P * N;
  int nseed = out_size;   // OUT=1 per reference

  size_t off = 0;
  auto alloc = [&](size_t bytes) {
    void* p = (char*)d_ws + off;
    off += (bytes + 255) & ~(size_t)255;
    return p;
  };
  unsigned short* x_bf = (unsigned short*)alloc((size_t)N * CD * 2);
  unsigned short* h_bf = (unsigned short*)alloc((size_t)N * CD * 2);   // compact rows
  float*          x32  = (float*)alloc((size_t)nseed * CD * 4);
  unsigned short* wt   = (unsigned short*)alloc(2 * 32768 * 2);
  int* deg_pd   = (int*)alloc((size_t)M * 4);
  int* row_ptr  = (int*)alloc((size_t)M * 4);
  int* col      = (int*)alloc((size_t)E * 4);
  int* col2     = (int*)alloc((size_t)E * 4);
  unsigned char* inv = (unsigned char*)alloc((size_t)M);   // [p][node] flags
  int* nlist    = (int*)alloc((size_t)M * 4);
  int* cidx     = (int*)alloc((size_t)M * 4);
  int* ncnt     = (int*)alloc(256);
  int* bsums    = (int*)alloc(4096);

  int NB2 = (N + 255) / 256;               // compaction blocks
  int M2 = 4 * NB2;                        // bcnt/bexc length
  int* bcnt = (int*)alloc((size_t)M2 * 4);
  int* bexc = (int*)alloc((size_t)M2 * 4);
  (void)ws_size;

  hipMemsetAsync(deg_pd, 0, (size_t)M * 4, stream);
  hipMemsetAsync(inv, 0, (size_t)M, stream);

  int egrid = (E + 255) / 256;
  int NB = (M + 1023) / 1024;
  int NBc = (M2 + 1023) / 1024;
  int ggrid = (N + 255) / 256;             // 256 rows per gemm block

  xprep<<<(N * 16 + 255) / 256, 256, 0, stream>>>(x, x_bf, x32, nseed, N * 16);
  wprep<<<(8192 + 255) / 256, 256, 0, stream>>>(wroot, wnbr, wt, 8192);
  histk<<<egrid, 256, 0, stream>>>(ntime, eidx, deg_pd, inv, minp, up, N, E);

  // compaction: count -> scan -> scatter (+ node->gi map, + ncnt totals)
  compcnt<<<NB2, 256, 0, stream>>>(inv, bcnt, NB2, N);
  scan1<<<NBc, 256, 0, stream>>>(bcnt, bexc, bsums, M2);
  scan2<<<1, 256, 0, stream>>>(bsums, NBc);
  scan3<<<NBc, 256, 0, stream>>>(bexc, bsums, M2);
  compscat<<<NB2, 256, 0, stream>>>(inv, bcnt, bexc, nlist, cidx, ncnt, NB2, N);

  // CSR build (cursor mechanism: row_ptr advances to bucket ends)
  scan1<<<NB, 256, 0, stream>>>(deg_pd, row_ptr, bsums, M);
  scan2<<<1, 256, 0, stream>>>(bsums, NB);
  scan3<<<NB, 256, 0, stream>>>(row_ptr, bsums, M);
  fillk<<<egrid, 256, 0, stream>>>(ntime, eidx, row_ptr, col, minp, up, N, E);
  remapk<<<egrid, 256, 0, stream>>>(col, col2, cidx, row_ptr, N, E);

  for (int p = 0; p < P; ++p) {
    const int* nlp = nlist + (size_t)p * N;
    const int* pc  = ncnt + p;
    gemm_fused<<<ggrid, 512, 0, stream>>>(x_bf, wt,
        bias, lng, lnb, h_bf, nullptr, nullptr, nlp, pc,
        deg_pd, row_ptr, col, p, N, 0, nseed);
    gemm_fused<<<ggrid, 512, 0, stream>>>(h_bf, wt + 32768,
        bias + CD, lng + CD, lnb + CD, nullptr, x32, x_bf, nlp, pc,
        deg_pd, row_ptr, col2, p, N, 1, nseed);
  }
  headk<<<(nseed + 3) / 4, 256, 0, stream>>>(x32, headw, headb, (float*)d_out, nseed);
}

// Round 11
// 582.684 us; speedup vs baseline: 1.1869x; 1.1090x over previous
//
#include <hip/hip_runtime.h>

// Temporal GraphSAGE, P=4 periods, C=128, L=2 (reference constants).
// R16: DEGREE-SORTED row lists. R14/R15 post-mortem: occupancy surgery
// (8 vs 16 waves/CU) moved nothing -> the stall is intra-wave: the CSR
// gather loop runs max(dg) over the 16 rows (l15 lanes) of each wave-group
// with lanes masked (E[max16 of Poisson(1.4)] ~ 4.5 vs mean 1.4 = ~3x
// waste). Fix: bucket-sort each period's compact list by degree
// (descending, 32 buckets) via the existing count/scan/scatter machinery.
// Row-independent math + unchanged CSR order => bitwise-identical output.
// Base = R13's proven 256-thread gemm (621us, no spill).
// Carried: fused CSR gather into A2 fragments (f32 ascending order,
// start=row_ptr-dg); cursor-atomic fillk; permuted channel layout
// pi(c)=(c&15)*8+(c>>4); compact h rows; 64KB LDS weight panel; byte
// involvement flags; scan-based compaction; remapk via bucket ends.

#define CD 128

typedef __attribute__((ext_vector_type(8))) short s16x8;
typedef __attribute__((ext_vector_type(4))) float f32x4;

static __device__ __forceinline__ unsigned short f2bf(float f) {
  unsigned u = __float_as_uint(f);
  u += 0x7FFF + ((u >> 16) & 1);   // round-to-nearest-even
  return (unsigned short)(u >> 16);
}
static __device__ __forceinline__ float bf2f(unsigned us) {
  return __uint_as_float(us << 16);
}
static __device__ __forceinline__ void acc8(float* a, uint4 v) {
  a[0] += bf2f(v.x & 0xffffu); a[1] += bf2f(v.x >> 16);
  a[2] += bf2f(v.y & 0xffffu); a[3] += bf2f(v.y >> 16);
  a[4] += bf2f(v.z & 0xffffu); a[5] += bf2f(v.z >> 16);
  a[6] += bf2f(v.w & 0xffffu); a[7] += bf2f(v.w >> 16);
}
static __device__ __forceinline__ s16x8 pack8(const float* a, float sc) {
  s16x8 r;
#pragma unroll
  for (int j = 0; j < 8; ++j) r[j] = (short)f2bf(a[j] * sc);
  return r;
}

// ---- histogram: per-(period,dst) degree (atomic) + involvement bytes ----
__global__ __launch_bounds__(256) void histk(const int* __restrict__ ntime,
    const int* __restrict__ eidx, int* __restrict__ deg_pd,
    unsigned char* __restrict__ inv,
    const int* __restrict__ minp, const int* __restrict__ up, int N, int E) {
  int e = blockIdx.x * 256 + threadIdx.x;
  if (e >= E) return;
  int s = eidx[e], d = eidx[E + e];
  int ts = ntime[s], td = ntime[d];
  int m = ts > td ? ts : td;
  int p = (m - minp[0]) / up[0];
  atomicAdd(&deg_pd[p * N + d], 1);
  inv[(size_t)p * N + s] = 1;   // benign race: all writers store 1
  inv[(size_t)p * N + d] = 1;
}

// ---- compaction pass 1: per-block per-period involved counts ----
__global__ __launch_bounds__(256) void compcnt(const unsigned char* __restrict__ inv,
    int* __restrict__ bcnt, int NB2, int N) {
  int i = blockIdx.x * 256 + threadIdx.x;
  int bits = 0;
  if (i < N)
    bits = (int)inv[i] | ((int)inv[N + i] << 1)
         | ((int)inv[2 * (size_t)N + i] << 2) | ((int)inv[3 * (size_t)N + i] << 3);
  int wv = threadIdx.x >> 6;
  int lane = threadIdx.x & 63;
  __shared__ int wcnt[4][4];   // [period][wave]
#pragma unroll
  for (int p = 0; p < 4; ++p) {
    unsigned long long m = __ballot((bits >> p) & 1);
    if (lane == 0) wcnt[p][wv] = __popcll(m);
  }
  __syncthreads();
  if (threadIdx.x < 4) {
    int p = threadIdx.x;
    bcnt[p * NB2 + blockIdx.x] = wcnt[p][0] + wcnt[p][1] + wcnt[p][2] + wcnt[p][3];
  }
}

// ---- compaction pass 3: deterministic scatter + ncnt totals ----
__global__ __launch_bounds__(256) void compscat(const unsigned char* __restrict__ inv,
    const int* __restrict__ bcnt, const int* __restrict__ bexc,
    int* __restrict__ nlist, int* __restrict__ ncnt,
    int NB2, int N) {
  int i = blockIdx.x * 256 + threadIdx.x;
  int bits = 0;
  if (i < N)
    bits = (int)inv[i] | ((int)inv[N + i] << 1)
         | ((int)inv[2 * (size_t)N + i] << 2) | ((int)inv[3 * (size_t)N + i] << 3);
  if (blockIdx.x == 0 && threadIdx.x < 4) {
    int p = threadIdx.x;
    ncnt[p] = bexc[p * NB2 + NB2 - 1] + bcnt[p * NB2 + NB2 - 1] - bexc[p * NB2];
  }
  int wv = threadIdx.x >> 6;
  int lane = threadIdx.x & 63;
  unsigned long long lanes_below = (lane == 0) ? 0ull : ((~0ull) >> (64 - lane));
  __shared__ int wcnt[4][4];
  unsigned long long mm[4];
#pragma unroll
  for (int p = 0; p < 4; ++p) {
    mm[p] = __ballot((bits >> p) & 1);
    if (lane == 0) wcnt[p][wv] = __popcll(mm[p]);
  }
  __syncthreads();
#pragma unroll
  for (int p = 0; p < 4; ++p) {
    if (!((bits >> p) & 1)) continue;
    int wpre = (wv > 0 ? wcnt[p][0] : 0) + (wv > 1 ? wcnt[p][1] : 0)
             + (wv > 2 ? wcnt[p][2] : 0);
    int base = bexc[p * NB2 + blockIdx.x] - bexc[p * NB2];
    int pos = base + wpre + __popcll(mm[p] & lanes_below);
    nlist[p * N + pos] = i;
  }
}

// ---- degree-sort pass 1: per-block per-(period,bucket) counts ----
// bucket = 31 - min(dg,31)  (descending degree order)
__global__ __launch_bounds__(256) void dhist(const int* __restrict__ nlist,
    const int* __restrict__ ncnt, const int* __restrict__ deg_pd,
    int* __restrict__ bcnt2, int NB2, int N) {
  __shared__ int cnt[4][32];
  int tid = threadIdx.x;
  if (tid < 128) ((int*)cnt)[tid] = 0;
  __syncthreads();
  int gi = blockIdx.x * 256 + tid;
#pragma unroll
  for (int p = 0; p < 4; ++p) {
    if (gi < ncnt[p]) {
      int d = nlist[p * N + gi];
      int dg = deg_pd[p * N + d];
      int b = 31 - (dg < 31 ? dg : 31);
      atomicAdd(&cnt[p][b], 1);
    }
  }
  __syncthreads();
  if (tid < 128) {
    int p = tid >> 5, b = tid & 31;
    bcnt2[(p * 32 + b) * NB2 + blockIdx.x] = cnt[p][b];
  }
}

// ---- degree-sort pass 2: scatter into nlist2 + node->pos map cidx2 ----
__global__ __launch_bounds__(256) void dscat(const int* __restrict__ nlist,
    const int* __restrict__ ncnt, const int* __restrict__ deg_pd,
    const int* __restrict__ bexc2, int* __restrict__ nlist2,
    int* __restrict__ cidx2, int NB2, int N) {
  __shared__ int cnt[4][32];
  int tid = threadIdx.x;
  if (tid < 128) ((int*)cnt)[tid] = 0;
  __syncthreads();
  int gi = blockIdx.x * 256 + tid;
#pragma unroll
  for (int p = 0; p < 4; ++p) {
    if (gi < ncnt[p]) {
      int node = nlist[p * N + gi];
      int dg = deg_pd[p * N + node];
      int b = 31 - (dg < 31 ? dg : 31);
      int r = atomicAdd(&cnt[p][b], 1);   // intra-block rank (any order OK)
      int base = bexc2[(p * 32 + b) * NB2 + blockIdx.x] - bexc2[p * 32 * NB2];
      int pos = base + r;
      nlist2[p * N + pos] = node;
      cidx2[p * N + node] = pos;
    }
  }
}

// ---- exclusive scan (3-phase) ----
__global__ __launch_bounds__(256) void scan1(const int* __restrict__ in,
    int* __restrict__ out, int* __restrict__ bsums, int M) {
  __shared__ int lds[256];
  int tid = threadIdx.x;
  int base = blockIdx.x * 1024 + tid * 4;
  int v0 = base + 0 < M ? in[base + 0] : 0;
  int v1 = base + 1 < M ? in[base + 1] : 0;
  int v2 = base + 2 < M ? in[base + 2] : 0;
  int v3 = base + 3 < M ? in[base + 3] : 0;
  int s = v0 + v1 + v2 + v3;
  lds[tid] = s;
  __syncthreads();
  for (int off = 1; off < 256; off <<= 1) {
    int t = tid >= off ? lds[tid - off] : 0;
    __syncthreads();
    lds[tid] += t;
    __syncthreads();
  }
  int run = lds[tid] - s;
  if (base + 0 < M) out[base + 0] = run; run += v0;
  if (base + 1 < M) out[base + 1] = run; run += v1;
  if (base + 2 < M) out[base + 2] = run; run += v2;
  if (base + 3 < M) out[base + 3] = run;
  if (tid == 255) bsums[blockIdx.x] = lds[255];
}

__global__ __launch_bounds__(256) void scan2(int* __restrict__ b, int M) {
  __shared__ int lds[256];
  int tid = threadIdx.x;
  int base = tid * 4;
  int v0 = base + 0 < M ? b[base + 0] : 0;
  int v1 = base + 1 < M ? b[base + 1] : 0;
  int v2 = base + 2 < M ? b[base + 2] : 0;
  int v3 = base + 3 < M ? b[base + 3] : 0;
  int s = v0 + v1 + v2 + v3;
  lds[tid] = s;
  __syncthreads();
  for (int off = 1; off < 256; off <<= 1) {
    int t = tid >= off ? lds[tid - off] : 0;
    __syncthreads();
    lds[tid] += t;
    __syncthreads();
  }
  int run = lds[tid] - s;
  if (base + 0 < M) b[base + 0] = run; run += v0;
  if (base + 1 < M) b[base + 1] = run; run += v1;
  if (base + 2 < M) b[base + 2] = run; run += v2;
  if (base + 3 < M) b[base + 3] = run;
}

__global__ __launch_bounds__(256) void scan3(int* __restrict__ out,
    const int* __restrict__ bsums, int M) {
  int add = bsums[blockIdx.x];
  int idx = blockIdx.x * 1024 + threadIdx.x;
#pragma unroll
  for (int k = 0; k < 4; ++k) {
    int i = idx + k * 256;
    if (i < M) out[i] += add;
  }
}

// ---- fill CSR col array; row_ptr doubles as cursor (R10 mechanism) ----
__global__ __launch_bounds__(256) void fillk(const int* __restrict__ ntime,
    const int* __restrict__ eidx, int* __restrict__ row_ptr, int* __restrict__ col,
    const int* __restrict__ minp, const int* __restrict__ up, int N, int E) {
  int e = blockIdx.x * 256 + threadIdx.x;
  if (e >= E) return;
  int s = eidx[e], d = eidx[E + e];
  int ts = ntime[s], td = ntime[d];
  int m = ts > td ? ts : td;
  int p = (m - minp[0]) / up[0];
  int pos = atomicAdd(&row_ptr[p * N + d], 1);
  col[pos] = s;
}

// ---- translate layer2 sources: col (node id) -> col2 (compact gi) ----
// row_ptr is post-cursor (bucket ENDS): period p ends at row_ptr[(p+1)*N-1].
__global__ __launch_bounds__(256) void remapk(const int* __restrict__ col,
    int* __restrict__ col2, const int* __restrict__ cidx,
    const int* __restrict__ row_ptr, int N, int E) {
  int i = blockIdx.x * 256 + threadIdx.x;
  if (i >= E) return;
  int p = (i >= row_ptr[N - 1]) + (i >= row_ptr[2 * N - 1]) + (i >= row_ptr[3 * N - 1]);
  col2[i] = cidx[(size_t)p * N + col[i]];
}

// ---- weights: bf16, fragment-linear, K-rows PERMUTED to match pi-layout ----
__global__ __launch_bounds__(256) void wprep(const float* __restrict__ wroot,
    const float* __restrict__ wnbr, unsigned short* __restrict__ wt, int total) {
  int t = blockIdx.x * 256 + threadIdx.x;
  if (t >= total) return;
  int l = t >> 12;
  int rem = t & 4095;
  int q = rem >> 7;
  int n = rem & 127;
  const float* src = (q < 16) ? (wroot + l * CD * CD) : (wnbr + l * CD * CD);
  int qh = q & 15;
  unsigned short o[8];
#pragma unroll
  for (int j = 0; j < 8; ++j) {
    int kp = qh * 8 + j;                 // permuted k within half
    int kt = (kp & 7) * 16 + (kp >> 3);  // true k
    o[j] = f2bf(src[kt * CD + n]);
  }
  uint4 pk;
  pk.x = (unsigned)o[0] | ((unsigned)o[1] << 16);
  pk.y = (unsigned)o[2] | ((unsigned)o[3] << 16);
  pk.z = (unsigned)o[4] | ((unsigned)o[5] << 16);
  pk.w = (unsigned)o[6] | ((unsigned)o[7] << 16);
  *(uint4*)(wt + (size_t)l * 32768 + ((size_t)q * CD + n) * 8) = pk;
}

// ---- x_bf init (permuted layout) + fp32 seed mirror ----
__global__ __launch_bounds__(256) void xprep(const float* __restrict__ x,
    unsigned short* __restrict__ xb, float* __restrict__ x32, int nseed, int total) {
  int t = blockIdx.x * 256 + threadIdx.x;
  if (t >= total) return;            // total = N*16
  int row = t >> 4, j = t & 15;
  const float* xp = x + (size_t)row * CD + j;
  bool seed = row < nseed;
  float* x3 = x32 + (size_t)row * CD + j;
  unsigned short o[8];
#pragma unroll
  for (int tt = 0; tt < 8; ++tt) {
    float v = xp[tt * 16];
    o[tt] = f2bf(v);
    if (seed) x3[tt * 16] = v;
  }
  uint4 pk;
  pk.x = (unsigned)o[0] | ((unsigned)o[1] << 16);
  pk.y = (unsigned)o[2] | ((unsigned)o[3] << 16);
  pk.z = (unsigned)o[4] | ((unsigned)o[5] << 16);
  pk.w = (unsigned)o[6] | ((unsigned)o[7] << 16);
  *(uint4*)(xb + (size_t)row * CD + j * 8) = pk;
}

// ---- FUSED gather-aggregate + MFMA GEMM + bias + LN ----
// Rows = degree-sorted compact list. A2 = mean over CSR neighbors,
// f32-accumulated in ascending CSR order, start = row_ptr[key]-dg
// ==> bitwise-identical to R13/R10 output.
__global__ __launch_bounds__(256, 2) void gemm_fused(
    const unsigned short* __restrict__ feat,
    const unsigned short* __restrict__ wt,
    const float* __restrict__ bias, const float* __restrict__ lng,
    const float* __restrict__ lnb,
    unsigned short* __restrict__ hout,
    float* __restrict__ x32, unsigned short* __restrict__ xbf,
    const int* __restrict__ nlp, const int* __restrict__ pcnt,
    const int* __restrict__ deg_pd, const int* __restrict__ row_ptr,
    const int* __restrict__ cols,
    int p, int N, int mode, int nseed) {
  int cnt = pcnt[0];
  int rbase = blockIdx.x * 128;
  if (rbase >= cnt) return;

  __shared__ unsigned short Blds[32768];   // 64 KB: whole layer weight panel
  {
    const uint4* src = (const uint4*)wt;
    uint4* dst = (uint4*)Blds;
#pragma unroll
    for (int i = 0; i < 16; ++i) dst[threadIdx.x + i * 256] = src[threadIdx.x + i * 256];
  }
  // barrier deferred until after gather (gather doesn't touch LDS)

  int tid = threadIdx.x;
  int w = tid >> 6;
  int lane = tid & 63;
  int l15 = lane & 15;
  int quad = lane >> 4;

  // per-lane A rows + CSR metadata (clamped; dup work discarded in epilogue;
  // descending degree sort makes clamp rows the dg=0 ones)
  int dg_[2], st_[2];
  const unsigned short* b1[2];
#pragma unroll
  for (int rt = 0; rt < 2; ++rt) {
    int ii = rbase + w * 32 + rt * 16 + l15;
    ii = ii < cnt ? ii : cnt - 1;
    int node = nlp[ii];
    int key = p * N + node;
    int dg = deg_pd[key];
    dg_[rt] = dg;
    st_[rt] = row_ptr[key] - dg;          // cursor end - deg = bucket start
    b1[rt] = feat + (size_t)(mode == 0 ? node : ii) * CD;
  }

  s16x8 af[4][2][2];
  // A1 fragments (kc 0..1)
#pragma unroll
  for (int kc = 0; kc < 2; ++kc)
#pragma unroll
    for (int ks = 0; ks < 2; ++ks) {
      int off = kc * 64 + (ks * 4 + quad) * 8;
#pragma unroll
      for (int rt = 0; rt < 2; ++rt)
        af[kc][ks][rt] = *(const s16x8*)(b1[rt] + off);
    }

  // A2 fragments (kc 2..3): fused CSR gather + mean (f32, ascending order)
  int cb = quad * 8;
#pragma unroll
  for (int rt = 0; rt < 2; ++rt) {
    float a0[8], a1[8], a2[8], a3[8];
#pragma unroll
    for (int j = 0; j < 8; ++j) { a0[j] = 0.f; a1[j] = 0.f; a2[j] = 0.f; a3[j] = 0.f; }
    int dg = dg_[rt], st = st_[rt];
    for (int j = 0; j < dg; ++j) {
      int r = cols[st + j];
      const unsigned short* rp = feat + (size_t)r * CD;
      uint4 v0 = *(const uint4*)(rp + cb);
      uint4 v1 = *(const uint4*)(rp + cb + 32);
      uint4 v2 = *(const uint4*)(rp + cb + 64);
      uint4 v3 = *(const uint4*)(rp + cb + 96);
      acc8(a0, v0); acc8(a1, v1); acc8(a2, v2); acc8(a3, v3);
    }
    float sc = dg > 0 ? 1.0f / (float)dg : 0.f;
    af[2][0][rt] = pack8(a0, sc);
    af[2][1][rt] = pack8(a1, sc);
    af[3][0][rt] = pack8(a2, sc);
    af[3][1][rt] = pack8(a3, sc);
  }

  __syncthreads();   // B panel ready (staged during gather)

  f32x4 acc[2][8];
#pragma unroll
  for (int rt = 0; rt < 2; ++rt)
#pragma unroll
    for (int ct = 0; ct < 8; ++ct) acc[rt][ct] = (f32x4)(0.f);

#pragma unroll
  for (int kc = 0; kc < 4; ++kc) {
#pragma unroll
    for (int ks = 0; ks < 2; ++ks) {
      int q = kc * 8 + ks * 4 + quad;        // global 16B k-block in [0,32)
      s16x8 bfr[8];
#pragma unroll
      for (int ct = 0; ct < 8; ++ct)
        bfr[ct] = *(const s16x8*)&Blds[((size_t)q * CD + l15) * 8 + (size_t)ct * 128];
#pragma unroll
      for (int rt = 0; rt < 2; ++rt)
#pragma unroll
        for (int ct = 0; ct < 8; ++ct)
          acc[rt][ct] = __builtin_amdgcn_mfma_f32_16x16x32_bf16(
              af[kc][ks][rt], bfr[ct], acc[rt][ct], 0, 0, 0);
    }
  }

  // epilogue: bias + LayerNorm across the 16-lane row group (true col = ct*16+l15)
  float bb[8], gg[8], eb[8];
#pragma unroll
  for (int ct = 0; ct < 8; ++ct) {
    int c = ct * 16 + l15;
    bb[ct] = bias[c]; gg[ct] = lng[c]; eb[ct] = lnb[c];
  }
#pragma unroll
  for (int rt = 0; rt < 2; ++rt) {
#pragma unroll
    for (int reg = 0; reg < 4; ++reg) {
      int ridx = rbase + w * 32 + rt * 16 + quad * 4 + reg;
      float vals[8];
      float s = 0.f, ss = 0.f;
#pragma unroll
      for (int ct = 0; ct < 8; ++ct) {
        float v = acc[rt][ct][reg] + bb[ct];
        vals[ct] = v;
        s += v; ss += v * v;
      }
#pragma unroll
      for (int m = 1; m <= 8; m <<= 1) {
        s  += __shfl_xor(s, m, 64);
        ss += __shfl_xor(ss, m, 64);
      }
      float mu  = s * (1.0f / CD);
      float var = ss * (1.0f / CD) - mu * mu;
      float rs  = rsqrtf(var + 1e-5f);
      if (ridx < cnt) {
        float o[8];
#pragma unroll
        for (int ct = 0; ct < 8; ++ct) o[ct] = (vals[ct] - mu) * rs * gg[ct] + eb[ct];
        if (mode == 0) {
          uint4 pk;
          pk.x = (unsigned)f2bf(fmaxf(o[0], 0.f)) | ((unsigned)f2bf(fmaxf(o[1], 0.f)) << 16);
          pk.y = (unsigned)f2bf(fmaxf(o[2], 0.f)) | ((unsigned)f2bf(fmaxf(o[3], 0.f)) << 16);
          pk.z = (unsigned)f2bf(fmaxf(o[4], 0.f)) | ((unsigned)f2bf(fmaxf(o[5], 0.f)) << 16);
          pk.w = (unsigned)f2bf(fmaxf(o[6], 0.f)) | ((unsigned)f2bf(fmaxf(o[7], 0.f)) << 16);
          *(uint4*)(hout + (size_t)ridx * CD + l15 * 8) = pk;   // compact, sequential
        } else {
          int node = nlp[ridx];
          unsigned short* xp = xbf + (size_t)node * CD + l15 * 8;
          uint4 old = *(const uint4*)xp;
          float xn0 = bf2f(old.x & 0xffffu) + o[0], xn1 = bf2f(old.x >> 16) + o[1];
          float xn2 = bf2f(old.y & 0xffffu) + o[2], xn3 = bf2f(old.y >> 16) + o[3];
          float xn4 = bf2f(old.z & 0xffffu) + o[4], xn5 = bf2f(old.z >> 16) + o[5];
          float xn6 = bf2f(old.w & 0xffffu) + o[6], xn7 = bf2f(old.w >> 16) + o[7];
          uint4 pk;
          pk.x = (unsigned)f2bf(xn0) | ((unsigned)f2bf(xn1) << 16);
          pk.y = (unsigned)f2bf(xn2) | ((unsigned)f2bf(xn3) << 16);
          pk.z = (unsigned)f2bf(xn4) | ((unsigned)f2bf(xn5) << 16);
          pk.w = (unsigned)f2bf(xn6) | ((unsigned)f2bf(xn7) << 16);
          *(uint4*)xp = pk;
          if (node < nseed) {
            float* x3 = x32 + (size_t)node * CD + l15;
#pragma unroll
            for (int ct = 0; ct < 8; ++ct) x3[ct * 16] += o[ct];
          }
        }
      }
    }
  }
}

// ---- head (reads fp32 seed mirror, original layout) ----
__global__ __launch_bounds__(256) void headk(const float* __restrict__ x,
    const float* __restrict__ hw, const float* __restrict__ hb,
    float* __restrict__ out, int seeds) {
  int wave = threadIdx.x >> 6;
  int lane = threadIdx.x & 63;
  int row = blockIdx.x * 4 + wave;
  if (row >= seeds) return;
  const float* xp = x + (size_t)row * CD;
  float v = xp[lane] * hw[lane] + xp[64 + lane] * hw[64 + lane];
#pragma unroll
  for (int m = 1; m < 64; m <<= 1) v += __shfl_xor(v, m, 64);
  if (lane == 0) out[row] = v + hb[0];
}

extern "C" void kernel_launch(void* const* d_in, const int* in_sizes, int n_in,
                              void* d_out, int out_size, void* d_ws, size_t ws_size,
                              hipStream_t stream) {
  const float* x     = (const float*)d_in[0];
  const int*   ntime = (const int*)d_in[1];
  const int*   eidx  = (const int*)d_in[2];
  const float* wroot = (const float*)d_in[3];
  const float* wnbr  = (const float*)d_in[4];
  const float* bias  = (const float*)d_in[5];
  const float* lng   = (const float*)d_in[6];
  const float* lnb   = (const float*)d_in[7];
  const float* headw = (const float*)d_in[8];
  const float* headb = (const float*)d_in[9];
  const int*   minp  = (const int*)d_in[10];
  const int*   up    = (const int*)d_in[12];

  int N = in_sizes[0] / CD;
  int E = in_sizes[2] / 2;
  const int P = 4;
  int M = P * N;
  int nseed = out_size;   // OUT=1 per reference

  size_t off = 0;
  auto alloc = [&](size_t bytes) {
    void* p = (char*)d_ws + off;
    off += (bytes + 255) & ~(size_t)255;
    return p;
  };
  unsigned short* x_bf = (unsigned short*)alloc((size_t)N * CD * 2);
  unsigned short* h_bf = (unsigned short*)alloc((size_t)N * CD * 2);   // compact rows
  float*          x32  = (float*)alloc((size_t)nseed * CD * 4);
  unsigned short* wt   = (unsigned short*)alloc(2 * 32768 * 2);
  int* deg_pd   = (int*)alloc((size_t)M * 4);
  int* row_ptr  = (int*)alloc((size_t)M * 4);
  int* col      = (int*)alloc((size_t)E * 4);
  int* col2     = (int*)alloc((size_t)E * 4);
  unsigned char* inv = (unsigned char*)alloc((size_t)M);   // [p][node] flags
  int* nlist    = (int*)alloc((size_t)M * 4);
  int* nlist2   = (int*)alloc((size_t)M * 4);   // degree-sorted
  int* cidx2    = (int*)alloc((size_t)M * 4);   // node -> sorted pos
  int* ncnt     = (int*)alloc(256);
  int* bsums    = (int*)alloc(4096);

  int NB2 = (N + 255) / 256;               // compaction blocks
  int M2 = 4 * NB2;                        // involvement counts length
  int M3 = 128 * NB2;                      // degree-bucket counts length
  int* bcnt  = (int*)alloc((size_t)M2 * 4);
  int* bexc  = (int*)alloc((size_t)M2 * 4);
  int* bcnt2 = (int*)alloc((size_t)M3 * 4);
  int* bexc2 = (int*)alloc((size_t)M3 * 4);
  (void)ws_size;

  hipMemsetAsync(deg_pd, 0, (size_t)M * 4, stream);
  hipMemsetAsync(inv, 0, (size_t)M, stream);

  int egrid = (E + 255) / 256;
  int NB = (M + 1023) / 1024;
  int NBc = (M2 + 1023) / 1024;
  int NBd = (M3 + 1023) / 1024;
  int ggrid = (N + 127) / 128;

  xprep<<<(N * 16 + 255) / 256, 256, 0, stream>>>(x, x_bf, x32, nseed, N * 16);
  wprep<<<(8192 + 255) / 256, 256, 0, stream>>>(wroot, wnbr, wt, 8192);
  histk<<<egrid, 256, 0, stream>>>(ntime, eidx, deg_pd, inv, minp, up, N, E);

  // compaction: count -> scan -> scatter (+ ncnt totals)
  compcnt<<<NB2, 256, 0, stream>>>(inv, bcnt, NB2, N);
  scan1<<<NBc, 256, 0, stream>>>(bcnt, bexc, bsums, M2);
  scan2<<<1, 256, 0, stream>>>(bsums, NBc);
  scan3<<<NBc, 256, 0, stream>>>(bexc, bsums, M2);
  compscat<<<NB2, 256, 0, stream>>>(inv, bcnt, bexc, nlist, ncnt, NB2, N);

  // degree sort (descending): count -> scan -> scatter (+ node->pos map)
  dhist<<<NB2, 256, 0, stream>>>(nlist, ncnt, deg_pd, bcnt2, NB2, N);
  scan1<<<NBd, 256, 0, stream>>>(bcnt2, bexc2, bsums, M3);
  scan2<<<1, 256, 0, stream>>>(bsums, NBd);
  scan3<<<NBd, 256, 0, stream>>>(bexc2, bsums, M3);
  dscat<<<NB2, 256, 0, stream>>>(nlist, ncnt, deg_pd, bexc2, nlist2, cidx2, NB2, N);

  // CSR build (cursor mechanism: row_ptr advances to bucket ends)
  scan1<<<NB, 256, 0, stream>>>(deg_pd, row_ptr, bsums, M);
  scan2<<<1, 256, 0, stream>>>(bsums, NB);
  scan3<<<NB, 256, 0, stream>>>(row_ptr, bsums, M);
  fillk<<<egrid, 256, 0, stream>>>(ntime, eidx, row_ptr, col, minp, up, N, E);
  remapk<<<egrid, 256, 0, stream>>>(col, col2, cidx2, row_ptr, N, E);

  for (int p = 0; p < P; ++p) {
    const int* nlp = nlist2 + (size_t)p * N;
    const int* pc  = ncnt + p;
    gemm_fused<<<ggrid, 256, 0, stream>>>(x_bf, wt,
        bias, lng, lnb, h_bf, nullptr, nullptr, nlp, pc,
        deg_pd, row_ptr, col, p, N, 0, nseed);
    gemm_fused<<<ggrid, 256, 0, stream>>>(h_bf, wt + 32768,
        bias + CD, lng + CD, lnb + CD, nullptr, x32, x_bf, nlp, pc,
        deg_pd, row_ptr, col2, p, N, 1, nseed);
  }
  headk<<<(nseed + 3) / 4, 256, 0, stream>>>(x32, headw, headb, (float*)d_out, nseed);
}

// Round 12
// 554.895 us; speedup vs baseline: 1.2463x; 1.0501x over previous
//
#include <hip/hip_runtime.h>

// Temporal GraphSAGE, P=4 periods, C=128, L=2 (reference constants).
// R17: latency-overlap bundle on R16 (582.7us). The two remaining exposed
// serial chains in gemm_fused: (1) gather's col->feat two-hop dependency
// -> software-pipelined (prefetch next col during current feat rounds);
// (2) mode-1 epilogue's scattered xbf RMW reads after all compute ->
// hoisted to kernel top (8 predicated uint4 loads fly under gather+MFMA).
// +40 VGPR, still under (256,2) cap; LDS-capped occupancy unchanged.
// Math/order/rounding bit-identical to R16.
// Carried: degree-sorted row lists (32-bucket desc sort); fused CSR gather
// into A2 fragments (f32 ascending order, start=row_ptr-dg); cursor-atomic
// fillk; permuted channel layout pi(c)=(c&15)*8+(c>>4); compact h rows;
// 64KB LDS weight panel; byte involvement flags; scan-based compaction.

#define CD 128

typedef __attribute__((ext_vector_type(8))) short s16x8;
typedef __attribute__((ext_vector_type(4))) float f32x4;

static __device__ __forceinline__ unsigned short f2bf(float f) {
  unsigned u = __float_as_uint(f);
  u += 0x7FFF + ((u >> 16) & 1);   // round-to-nearest-even
  return (unsigned short)(u >> 16);
}
static __device__ __forceinline__ float bf2f(unsigned us) {
  return __uint_as_float(us << 16);
}
static __device__ __forceinline__ void acc8(float* a, uint4 v) {
  a[0] += bf2f(v.x & 0xffffu); a[1] += bf2f(v.x >> 16);
  a[2] += bf2f(v.y & 0xffffu); a[3] += bf2f(v.y >> 16);
  a[4] += bf2f(v.z & 0xffffu); a[5] += bf2f(v.z >> 16);
  a[6] += bf2f(v.w & 0xffffu); a[7] += bf2f(v.w >> 16);
}
static __device__ __forceinline__ s16x8 pack8(const float* a, float sc) {
  s16x8 r;
#pragma unroll
  for (int j = 0; j < 8; ++j) r[j] = (short)f2bf(a[j] * sc);
  return r;
}

// ---- histogram: per-(period,dst) degree (atomic) + involvement bytes ----
__global__ __launch_bounds__(256) void histk(const int* __restrict__ ntime,
    const int* __restrict__ eidx, int* __restrict__ deg_pd,
    unsigned char* __restrict__ inv,
    const int* __restrict__ minp, const int* __restrict__ up, int N, int E) {
  int e = blockIdx.x * 256 + threadIdx.x;
  if (e >= E) return;
  int s = eidx[e], d = eidx[E + e];
  int ts = ntime[s], td = ntime[d];
  int m = ts > td ? ts : td;
  int p = (m - minp[0]) / up[0];
  atomicAdd(&deg_pd[p * N + d], 1);
  inv[(size_t)p * N + s] = 1;   // benign race: all writers store 1
  inv[(size_t)p * N + d] = 1;
}

// ---- compaction pass 1: per-block per-period involved counts ----
__global__ __launch_bounds__(256) void compcnt(const unsigned char* __restrict__ inv,
    int* __restrict__ bcnt, int NB2, int N) {
  int i = blockIdx.x * 256 + threadIdx.x;
  int bits = 0;
  if (i < N)
    bits = (int)inv[i] | ((int)inv[N + i] << 1)
         | ((int)inv[2 * (size_t)N + i] << 2) | ((int)inv[3 * (size_t)N + i] << 3);
  int wv = threadIdx.x >> 6;
  int lane = threadIdx.x & 63;
  __shared__ int wcnt[4][4];   // [period][wave]
#pragma unroll
  for (int p = 0; p < 4; ++p) {
    unsigned long long m = __ballot((bits >> p) & 1);
    if (lane == 0) wcnt[p][wv] = __popcll(m);
  }
  __syncthreads();
  if (threadIdx.x < 4) {
    int p = threadIdx.x;
    bcnt[p * NB2 + blockIdx.x] = wcnt[p][0] + wcnt[p][1] + wcnt[p][2] + wcnt[p][3];
  }
}

// ---- compaction pass 3: deterministic scatter + ncnt totals ----
__global__ __launch_bounds__(256) void compscat(const unsigned char* __restrict__ inv,
    const int* __restrict__ bcnt, const int* __restrict__ bexc,
    int* __restrict__ nlist, int* __restrict__ ncnt,
    int NB2, int N) {
  int i = blockIdx.x * 256 + threadIdx.x;
  int bits = 0;
  if (i < N)
    bits = (int)inv[i] | ((int)inv[N + i] << 1)
         | ((int)inv[2 * (size_t)N + i] << 2) | ((int)inv[3 * (size_t)N + i] << 3);
  if (blockIdx.x == 0 && threadIdx.x < 4) {
    int p = threadIdx.x;
    ncnt[p] = bexc[p * NB2 + NB2 - 1] + bcnt[p * NB2 + NB2 - 1] - bexc[p * NB2];
  }
  int wv = threadIdx.x >> 6;
  int lane = threadIdx.x & 63;
  unsigned long long lanes_below = (lane == 0) ? 0ull : ((~0ull) >> (64 - lane));
  __shared__ int wcnt[4][4];
  unsigned long long mm[4];
#pragma unroll
  for (int p = 0; p < 4; ++p) {
    mm[p] = __ballot((bits >> p) & 1);
    if (lane == 0) wcnt[p][wv] = __popcll(mm[p]);
  }
  __syncthreads();
#pragma unroll
  for (int p = 0; p < 4; ++p) {
    if (!((bits >> p) & 1)) continue;
    int wpre = (wv > 0 ? wcnt[p][0] : 0) + (wv > 1 ? wcnt[p][1] : 0)
             + (wv > 2 ? wcnt[p][2] : 0);
    int base = bexc[p * NB2 + blockIdx.x] - bexc[p * NB2];
    int pos = base + wpre + __popcll(mm[p] & lanes_below);
    nlist[p * N + pos] = i;
  }
}

// ---- degree-sort pass 1: per-block per-(period,bucket) counts ----
// bucket = 31 - min(dg,31)  (descending degree order)
__global__ __launch_bounds__(256) void dhist(const int* __restrict__ nlist,
    const int* __restrict__ ncnt, const int* __restrict__ deg_pd,
    int* __restrict__ bcnt2, int NB2, int N) {
  __shared__ int cnt[4][32];
  int tid = threadIdx.x;
  if (tid < 128) ((int*)cnt)[tid] = 0;
  __syncthreads();
  int gi = blockIdx.x * 256 + tid;
#pragma unroll
  for (int p = 0; p < 4; ++p) {
    if (gi < ncnt[p]) {
      int d = nlist[p * N + gi];
      int dg = deg_pd[p * N + d];
      int b = 31 - (dg < 31 ? dg : 31);
      atomicAdd(&cnt[p][b], 1);
    }
  }
  __syncthreads();
  if (tid < 128) {
    int p = tid >> 5, b = tid & 31;
    bcnt2[(p * 32 + b) * NB2 + blockIdx.x] = cnt[p][b];
  }
}

// ---- degree-sort pass 2: scatter into nlist2 + node->pos map cidx2 ----
__global__ __launch_bounds__(256) void dscat(const int* __restrict__ nlist,
    const int* __restrict__ ncnt, const int* __restrict__ deg_pd,
    const int* __restrict__ bexc2, int* __restrict__ nlist2,
    int* __restrict__ cidx2, int NB2, int N) {
  __shared__ int cnt[4][32];
  int tid = threadIdx.x;
  if (tid < 128) ((int*)cnt)[tid] = 0;
  __syncthreads();
  int gi = blockIdx.x * 256 + tid;
#pragma unroll
  for (int p = 0; p < 4; ++p) {
    if (gi < ncnt[p]) {
      int node = nlist[p * N + gi];
      int dg = deg_pd[p * N + node];
      int b = 31 - (dg < 31 ? dg : 31);
      int r = atomicAdd(&cnt[p][b], 1);   // intra-block rank (any order OK)
      int base = bexc2[(p * 32 + b) * NB2 + blockIdx.x] - bexc2[p * 32 * NB2];
      int pos = base + r;
      nlist2[p * N + pos] = node;
      cidx2[p * N + node] = pos;
    }
  }
}

// ---- exclusive scan (3-phase) ----
__global__ __launch_bounds__(256) void scan1(const int* __restrict__ in,
    int* __restrict__ out, int* __restrict__ bsums, int M) {
  __shared__ int lds[256];
  int tid = threadIdx.x;
  int base = blockIdx.x * 1024 + tid * 4;
  int v0 = base + 0 < M ? in[base + 0] : 0;
  int v1 = base + 1 < M ? in[base + 1] : 0;
  int v2 = base + 2 < M ? in[base + 2] : 0;
  int v3 = base + 3 < M ? in[base + 3] : 0;
  int s = v0 + v1 + v2 + v3;
  lds[tid] = s;
  __syncthreads();
  for (int off = 1; off < 256; off <<= 1) {
    int t = tid >= off ? lds[tid - off] : 0;
    __syncthreads();
    lds[tid] += t;
    __syncthreads();
  }
  int run = lds[tid] - s;
  if (base + 0 < M) out[base + 0] = run; run += v0;
  if (base + 1 < M) out[base + 1] = run; run += v1;
  if (base + 2 < M) out[base + 2] = run; run += v2;
  if (base + 3 < M) out[base + 3] = run;
  if (tid == 255) bsums[blockIdx.x] = lds[255];
}

__global__ __launch_bounds__(256) void scan2(int* __restrict__ b, int M) {
  __shared__ int lds[256];
  int tid = threadIdx.x;
  int base = tid * 4;
  int v0 = base + 0 < M ? b[base + 0] : 0;
  int v1 = base + 1 < M ? b[base + 1] : 0;
  int v2 = base + 2 < M ? b[base + 2] : 0;
  int v3 = base + 3 < M ? b[base + 3] : 0;
  int s = v0 + v1 + v2 + v3;
  lds[tid] = s;
  __syncthreads();
  for (int off = 1; off < 256; off <<= 1) {
    int t = tid >= off ? lds[tid - off] : 0;
    __syncthreads();
    lds[tid] += t;
    __syncthreads();
  }
  int run = lds[tid] - s;
  if (base + 0 < M) b[base + 0] = run; run += v0;
  if (base + 1 < M) b[base + 1] = run; run += v1;
  if (base + 2 < M) b[base + 2] = run; run += v2;
  if (base + 3 < M) b[base + 3] = run;
}

__global__ __launch_bounds__(256) void scan3(int* __restrict__ out,
    const int* __restrict__ bsums, int M) {
  int add = bsums[blockIdx.x];
  int idx = blockIdx.x * 1024 + threadIdx.x;
#pragma unroll
  for (int k = 0; k < 4; ++k) {
    int i = idx + k * 256;
    if (i < M) out[i] += add;
  }
}

// ---- fill CSR col array; row_ptr doubles as cursor (R10 mechanism) ----
__global__ __launch_bounds__(256) void fillk(const int* __restrict__ ntime,
    const int* __restrict__ eidx, int* __restrict__ row_ptr, int* __restrict__ col,
    const int* __restrict__ minp, const int* __restrict__ up, int N, int E) {
  int e = blockIdx.x * 256 + threadIdx.x;
  if (e >= E) return;
  int s = eidx[e], d = eidx[E + e];
  int ts = ntime[s], td = ntime[d];
  int m = ts > td ? ts : td;
  int p = (m - minp[0]) / up[0];
  int pos = atomicAdd(&row_ptr[p * N + d], 1);
  col[pos] = s;
}

// ---- translate layer2 sources: col (node id) -> col2 (compact gi) ----
// row_ptr is post-cursor (bucket ENDS): period p ends at row_ptr[(p+1)*N-1].
__global__ __launch_bounds__(256) void remapk(const int* __restrict__ col,
    int* __restrict__ col2, const int* __restrict__ cidx,
    const int* __restrict__ row_ptr, int N, int E) {
  int i = blockIdx.x * 256 + threadIdx.x;
  if (i >= E) return;
  int p = (i >= row_ptr[N - 1]) + (i >= row_ptr[2 * N - 1]) + (i >= row_ptr[3 * N - 1]);
  col2[i] = cidx[(size_t)p * N + col[i]];
}

// ---- weights: bf16, fragment-linear, K-rows PERMUTED to match pi-layout ----
__global__ __launch_bounds__(256) void wprep(const float* __restrict__ wroot,
    const float* __restrict__ wnbr, unsigned short* __restrict__ wt, int total) {
  int t = blockIdx.x * 256 + threadIdx.x;
  if (t >= total) return;
  int l = t >> 12;
  int rem = t & 4095;
  int q = rem >> 7;
  int n = rem & 127;
  const float* src = (q < 16) ? (wroot + l * CD * CD) : (wnbr + l * CD * CD);
  int qh = q & 15;
  unsigned short o[8];
#pragma unroll
  for (int j = 0; j < 8; ++j) {
    int kp = qh * 8 + j;                 // permuted k within half
    int kt = (kp & 7) * 16 + (kp >> 3);  // true k
    o[j] = f2bf(src[kt * CD + n]);
  }
  uint4 pk;
  pk.x = (unsigned)o[0] | ((unsigned)o[1] << 16);
  pk.y = (unsigned)o[2] | ((unsigned)o[3] << 16);
  pk.z = (unsigned)o[4] | ((unsigned)o[5] << 16);
  pk.w = (unsigned)o[6] | ((unsigned)o[7] << 16);
  *(uint4*)(wt + (size_t)l * 32768 + ((size_t)q * CD + n) * 8) = pk;
}

// ---- x_bf init (permuted layout) + fp32 seed mirror ----
__global__ __launch_bounds__(256) void xprep(const float* __restrict__ x,
    unsigned short* __restrict__ xb, float* __restrict__ x32, int nseed, int total) {
  int t = blockIdx.x * 256 + threadIdx.x;
  if (t >= total) return;            // total = N*16
  int row = t >> 4, j = t & 15;
  const float* xp = x + (size_t)row * CD + j;
  bool seed = row < nseed;
  float* x3 = x32 + (size_t)row * CD + j;
  unsigned short o[8];
#pragma unroll
  for (int tt = 0; tt < 8; ++tt) {
    float v = xp[tt * 16];
    o[tt] = f2bf(v);
    if (seed) x3[tt * 16] = v;
  }
  uint4 pk;
  pk.x = (unsigned)o[0] | ((unsigned)o[1] << 16);
  pk.y = (unsigned)o[2] | ((unsigned)o[3] << 16);
  pk.z = (unsigned)o[4] | ((unsigned)o[5] << 16);
  pk.w = (unsigned)o[6] | ((unsigned)o[7] << 16);
  *(uint4*)(xb + (size_t)row * CD + j * 8) = pk;
}

// ---- FUSED gather-aggregate + MFMA GEMM + bias + LN ----
// Rows = degree-sorted compact list. A2 = mean over CSR neighbors,
// f32-accumulated in ascending CSR order, start = row_ptr[key]-dg
// ==> bitwise-identical to R16/R13/R10 output.
// R17: col prefetch pipeline in the gather; mode-1 RMW reads hoisted.
__global__ __launch_bounds__(256, 2) void gemm_fused(
    const unsigned short* __restrict__ feat,
    const unsigned short* __restrict__ wt,
    const float* __restrict__ bias, const float* __restrict__ lng,
    const float* __restrict__ lnb,
    unsigned short* __restrict__ hout,
    float* __restrict__ x32, unsigned short* __restrict__ xbf,
    const int* __restrict__ nlp, const int* __restrict__ pcnt,
    const int* __restrict__ deg_pd, const int* __restrict__ row_ptr,
    const int* __restrict__ cols,
    int p, int N, int mode, int nseed) {
  int cnt = pcnt[0];
  int rbase = blockIdx.x * 128;
  if (rbase >= cnt) return;

  __shared__ unsigned short Blds[32768];   // 64 KB: whole layer weight panel
  {
    const uint4* src = (const uint4*)wt;
    uint4* dst = (uint4*)Blds;
#pragma unroll
    for (int i = 0; i < 16; ++i) dst[threadIdx.x + i * 256] = src[threadIdx.x + i * 256];
  }
  // barrier deferred until after gather (gather doesn't touch LDS)

  int tid = threadIdx.x;
  int w = tid >> 6;
  int lane = tid & 63;
  int l15 = lane & 15;
  int quad = lane >> 4;

  // per-lane A rows + CSR metadata (clamped; dup work discarded in epilogue;
  // descending degree sort makes clamp rows the dg=0 ones)
  int dg_[2], st_[2];
  const unsigned short* b1[2];
#pragma unroll
  for (int rt = 0; rt < 2; ++rt) {
    int ii = rbase + w * 32 + rt * 16 + l15;
    ii = ii < cnt ? ii : cnt - 1;
    int node = nlp[ii];
    int key = p * N + node;
    int dg = deg_pd[key];
    dg_[rt] = dg;
    st_[rt] = row_ptr[key] - dg;          // cursor end - deg = bucket start
    b1[rt] = feat + (size_t)(mode == 0 ? node : ii) * CD;
  }

  // R17: hoist mode-1 residual RMW reads (epilogue rows = quad*4+reg) so
  // their latency hides under the gather + MFMA phases. Clamped loads of
  // rows owned by other threads are read-only and discarded at write time.
  int ep_node[2][4];
  uint4 ep_old[2][4];
  if (mode != 0) {
#pragma unroll
    for (int rt = 0; rt < 2; ++rt)
#pragma unroll
      for (int reg = 0; reg < 4; ++reg) {
        int ridx = rbase + w * 32 + rt * 16 + quad * 4 + reg;
        int rr = ridx < cnt ? ridx : cnt - 1;
        int node = nlp[rr];
        ep_node[rt][reg] = node;
        ep_old[rt][reg] = *(const uint4*)(xbf + (size_t)node * CD + l15 * 8);
      }
  }

  s16x8 af[4][2][2];
  // A1 fragments (kc 0..1)
#pragma unroll
  for (int kc = 0; kc < 2; ++kc)
#pragma unroll
    for (int ks = 0; ks < 2; ++ks) {
      int off = kc * 64 + (ks * 4 + quad) * 8;
#pragma unroll
      for (int rt = 0; rt < 2; ++rt)
        af[kc][ks][rt] = *(const s16x8*)(b1[rt] + off);
    }

  // A2 fragments (kc 2..3): fused CSR gather + mean (f32, ascending order)
  // R17: software-pipelined col prefetch (next col load overlaps current
  // feat loads/adds -> per-round chain = max(col, feat), not col+feat).
  int cb = quad * 8;
#pragma unroll
  for (int rt = 0; rt < 2; ++rt) {
    float a0[8], a1[8], a2[8], a3[8];
#pragma unroll
    for (int j = 0; j < 8; ++j) { a0[j] = 0.f; a1[j] = 0.f; a2[j] = 0.f; a3[j] = 0.f; }
    int dg = dg_[rt], st = st_[rt];
    int r = dg > 0 ? cols[st] : 0;
    for (int j = 0; j < dg; ++j) {
      int rn = (j + 1 < dg) ? cols[st + j + 1] : 0;
      const unsigned short* rp = feat + (size_t)r * CD;
      uint4 v0 = *(const uint4*)(rp + cb);
      uint4 v1 = *(const uint4*)(rp + cb + 32);
      uint4 v2 = *(const uint4*)(rp + cb + 64);
      uint4 v3 = *(const uint4*)(rp + cb + 96);
      acc8(a0, v0); acc8(a1, v1); acc8(a2, v2); acc8(a3, v3);
      r = rn;
    }
    float sc = dg > 0 ? 1.0f / (float)dg : 0.f;
    af[2][0][rt] = pack8(a0, sc);
    af[2][1][rt] = pack8(a1, sc);
    af[3][0][rt] = pack8(a2, sc);
    af[3][1][rt] = pack8(a3, sc);
  }

  __syncthreads();   // B panel ready (staged during gather)

  f32x4 acc[2][8];
#pragma unroll
  for (int rt = 0; rt < 2; ++rt)
#pragma unroll
    for (int ct = 0; ct < 8; ++ct) acc[rt][ct] = (f32x4)(0.f);

#pragma unroll
  for (int kc = 0; kc < 4; ++kc) {
#pragma unroll
    for (int ks = 0; ks < 2; ++ks) {
      int q = kc * 8 + ks * 4 + quad;        // global 16B k-block in [0,32)
      s16x8 bfr[8];
#pragma unroll
      for (int ct = 0; ct < 8; ++ct)
        bfr[ct] = *(const s16x8*)&Blds[((size_t)q * CD + l15) * 8 + (size_t)ct * 128];
#pragma unroll
      for (int rt = 0; rt < 2; ++rt)
#pragma unroll
        for (int ct = 0; ct < 8; ++ct)
          acc[rt][ct] = __builtin_amdgcn_mfma_f32_16x16x32_bf16(
              af[kc][ks][rt], bfr[ct], acc[rt][ct], 0, 0, 0);
    }
  }

  // epilogue: bias + LayerNorm across the 16-lane row group (true col = ct*16+l15)
  float bb[8], gg[8], eb[8];
#pragma unroll
  for (int ct = 0; ct < 8; ++ct) {
    int c = ct * 16 + l15;
    bb[ct] = bias[c]; gg[ct] = lng[c]; eb[ct] = lnb[c];
  }
#pragma unroll
  for (int rt = 0; rt < 2; ++rt) {
#pragma unroll
    for (int reg = 0; reg < 4; ++reg) {
      int ridx = rbase + w * 32 + rt * 16 + quad * 4 + reg;
      float vals[8];
      float s = 0.f, ss = 0.f;
#pragma unroll
      for (int ct = 0; ct < 8; ++ct) {
        float v = acc[rt][ct][reg] + bb[ct];
        vals[ct] = v;
        s += v; ss += v * v;
      }
#pragma unroll
      for (int m = 1; m <= 8; m <<= 1) {
        s  += __shfl_xor(s, m, 64);
        ss += __shfl_xor(ss, m, 64);
      }
      float mu  = s * (1.0f / CD);
      float var = ss * (1.0f / CD) - mu * mu;
      float rs  = rsqrtf(var + 1e-5f);
      if (ridx < cnt) {
        float o[8];
#pragma unroll
        for (int ct = 0; ct < 8; ++ct) o[ct] = (vals[ct] - mu) * rs * gg[ct] + eb[ct];
        if (mode == 0) {
          uint4 pk;
          pk.x = (unsigned)f2bf(fmaxf(o[0], 0.f)) | ((unsigned)f2bf(fmaxf(o[1], 0.f)) << 16);
          pk.y = (unsigned)f2bf(fmaxf(o[2], 0.f)) | ((unsigned)f2bf(fmaxf(o[3], 0.f)) << 16);
          pk.z = (unsigned)f2bf(fmaxf(o[4], 0.f)) | ((unsigned)f2bf(fmaxf(o[5], 0.f)) << 16);
          pk.w = (unsigned)f2bf(fmaxf(o[6], 0.f)) | ((unsigned)f2bf(fmaxf(o[7], 0.f)) << 16);
          *(uint4*)(hout + (size_t)ridx * CD + l15 * 8) = pk;   // compact, sequential
        } else {
          int node = ep_node[rt][reg];
          uint4 old = ep_old[rt][reg];
          float xn0 = bf2f(old.x & 0xffffu) + o[0], xn1 = bf2f(old.x >> 16) + o[1];
          float xn2 = bf2f(old.y & 0xffffu) + o[2], xn3 = bf2f(old.y >> 16) + o[3];
          float xn4 = bf2f(old.z & 0xffffu) + o[4], xn5 = bf2f(old.z >> 16) + o[5];
          float xn6 = bf2f(old.w & 0xffffu) + o[6], xn7 = bf2f(old.w >> 16) + o[7];
          uint4 pk;
          pk.x = (unsigned)f2bf(xn0) | ((unsigned)f2bf(xn1) << 16);
          pk.y = (unsigned)f2bf(xn2) | ((unsigned)f2bf(xn3) << 16);
          pk.z = (unsigned)f2bf(xn4) | ((unsigned)f2bf(xn5) << 16);
          pk.w = (unsigned)f2bf(xn6) | ((unsigned)f2bf(xn7) << 16);
          *(uint4*)(xbf + (size_t)node * CD + l15 * 8) = pk;
          if (node < nseed) {
            float* x3 = x32 + (size_t)node * CD + l15;
#pragma unroll
            for (int ct = 0; ct < 8; ++ct) x3[ct * 16] += o[ct];
          }
        }
      }
    }
  }
}

// ---- head (reads fp32 seed mirror, original layout) ----
__global__ __launch_bounds__(256) void headk(const float* __restrict__ x,
    const float* __restrict__ hw, const float* __restrict__ hb,
    float* __restrict__ out, int seeds) {
  int wave = threadIdx.x >> 6;
  int lane = threadIdx.x & 63;
  int row = blockIdx.x * 4 + wave;
  if (row >= seeds) return;
  const float* xp = x + (size_t)row * CD;
  float v = xp[lane] * hw[lane] + xp[64 + lane] * hw[64 + lane];
#pragma unroll
  for (int m = 1; m < 64; m <<= 1) v += __shfl_xor(v, m, 64);
  if (lane == 0) out[row] = v + hb[0];
}

extern "C" void kernel_launch(void* const* d_in, const int* in_sizes, int n_in,
                              void* d_out, int out_size, void* d_ws, size_t ws_size,
                              hipStream_t stream) {
  const float* x     = (const float*)d_in[0];
  const int*   ntime = (const int*)d_in[1];
  const int*   eidx  = (const int*)d_in[2];
  const float* wroot = (const float*)d_in[3];
  const float* wnbr  = (const float*)d_in[4];
  const float* bias  = (const float*)d_in[5];
  const float* lng   = (const float*)d_in[6];
  const float* lnb   = (const float*)d_in[7];
  const float* headw = (const float*)d_in[8];
  const float* headb = (const float*)d_in[9];
  const int*   minp  = (const int*)d_in[10];
  const int*   up    = (const int*)d_in[12];

  int N = in_sizes[0] / CD;
  int E = in_sizes[2] / 2;
  const int P = 4;
  int M = P * N;
  int nseed = out_size;   // OUT=1 per reference

  size_t off = 0;
  auto alloc = [&](size_t bytes) {
    void* p = (char*)d_ws + off;
    off += (bytes + 255) & ~(size_t)255;
    return p;
  };
  unsigned short* x_bf = (unsigned short*)alloc((size_t)N * CD * 2);
  unsigned short* h_bf = (unsigned short*)alloc((size_t)N * CD * 2);   // compact rows
  float*          x32  = (float*)alloc((size_t)nseed * CD * 4);
  unsigned short* wt   = (unsigned short*)alloc(2 * 32768 * 2);
  int* deg_pd   = (int*)alloc((size_t)M * 4);
  int* row_ptr  = (int*)alloc((size_t)M * 4);
  int* col      = (int*)alloc((size_t)E * 4);
  int* col2     = (int*)alloc((size_t)E * 4);
  unsigned char* inv = (unsigned char*)alloc((size_t)M);   // [p][node] flags
  int* nlist    = (int*)alloc((size_t)M * 4);
  int* nlist2   = (int*)alloc((size_t)M * 4);   // degree-sorted
  int* cidx2    = (int*)alloc((size_t)M * 4);   // node -> sorted pos
  int* ncnt     = (int*)alloc(256);
  int* bsums    = (int*)alloc(4096);

  int NB2 = (N + 255) / 256;               // compaction blocks
  int M2 = 4 * NB2;                        // involvement counts length
  int M3 = 128 * NB2;                      // degree-bucket counts length
  int* bcnt  = (int*)alloc((size_t)M2 * 4);
  int* bexc  = (int*)alloc((size_t)M2 * 4);
  int* bcnt2 = (int*)alloc((size_t)M3 * 4);
  int* bexc2 = (int*)alloc((size_t)M3 * 4);
  (void)ws_size;

  hipMemsetAsync(deg_pd, 0, (size_t)M * 4, stream);
  hipMemsetAsync(inv, 0, (size_t)M, stream);

  int egrid = (E + 255) / 256;
  int NB = (M + 1023) / 1024;
  int NBc = (M2 + 1023) / 1024;
  int NBd = (M3 + 1023) / 1024;
  int ggrid = (N + 127) / 128;

  xprep<<<(N * 16 + 255) / 256, 256, 0, stream>>>(x, x_bf, x32, nseed, N * 16);
  wprep<<<(8192 + 255) / 256, 256, 0, stream>>>(wroot, wnbr, wt, 8192);
  histk<<<egrid, 256, 0, stream>>>(ntime, eidx, deg_pd, inv, minp, up, N, E);

  // compaction: count -> scan -> scatter (+ ncnt totals)
  compcnt<<<NB2, 256, 0, stream>>>(inv, bcnt, NB2, N);
  scan1<<<NBc, 256, 0, stream>>>(bcnt, bexc, bsums, M2);
  scan2<<<1, 256, 0, stream>>>(bsums, NBc);
  scan3<<<NBc, 256, 0, stream>>>(bexc, bsums, M2);
  compscat<<<NB2, 256, 0, stream>>>(inv, bcnt, bexc, nlist, ncnt, NB2, N);

  // degree sort (descending): count -> scan -> scatter (+ node->pos map)
  dhist<<<NB2, 256, 0, stream>>>(nlist, ncnt, deg_pd, bcnt2, NB2, N);
  scan1<<<NBd, 256, 0, stream>>>(bcnt2, bexc2, bsums, M3);
  scan2<<<1, 256, 0, stream>>>(bsums, NBd);
  scan3<<<NBd, 256, 0, stream>>>(bexc2, bsums, M3);
  dscat<<<NB2, 256, 0, stream>>>(nlist, ncnt, deg_pd, bexc2, nlist2, cidx2, NB2, N);

  // CSR build (cursor mechanism: row_ptr advances to bucket ends)
  scan1<<<NB, 256, 0, stream>>>(deg_pd, row_ptr, bsums, M);
  scan2<<<1, 256, 0, stream>>>(bsums, NB);
  scan3<<<NB, 256, 0, stream>>>(row_ptr, bsums, M);
  fillk<<<egrid, 256, 0, stream>>>(ntime, eidx, row_ptr, col, minp, up, N, E);
  remapk<<<egrid, 256, 0, stream>>>(col, col2, cidx2, row_ptr, N, E);

  for (int p = 0; p < P; ++p) {
    const int* nlp = nlist2 + (size_t)p * N;
    const int* pc  = ncnt + p;
    gemm_fused<<<ggrid, 256, 0, stream>>>(x_bf, wt,
        bias, lng, lnb, h_bf, nullptr, nullptr, nlp, pc,
        deg_pd, row_ptr, col, p, N, 0, nseed);
    gemm_fused<<<ggrid, 256, 0, stream>>>(h_bf, wt + 32768,
        bias + CD, lng + CD, lnb + CD, nullptr, x32, x_bf, nlp, pc,
        deg_pd, row_ptr, col2, p, N, 1, nseed);
  }
  headk<<<(nseed + 3) / 4, 256, 0, stream>>>(x32, headw, headb, (float*)d_out, nseed);
}